// Round 18
// baseline (212.581 us; speedup 1.0000x reference)
//
#include <hip/hip_runtime.h>
#include <hip/hip_bf16.h>
#include <stdint.h>

typedef uint16_t u16;
typedef __attribute__((ext_vector_type(4))) float f32x4;
typedef __attribute__((ext_vector_type(8))) short bf16x8;

#define LOG2E 1.4426950408889634f

static __device__ __forceinline__ u16 f2b(float x){
  union { float f; uint32_t u; } a; a.f = x;
  uint32_t r = a.u + 0x7FFFu + ((a.u >> 16) & 1u);
  return (u16)(r >> 16);
}

// pack two f32 -> two bf16 (round-half-up) in 3 VALU: add, add, v_perm_b32
static __device__ __forceinline__ uint32_t pkrhu(float lo, float hi){
  union { float f; uint32_t u; } a, b; a.f = lo; b.f = hi;
  return __builtin_amdgcn_perm(b.u + 0x8000u, a.u + 0x8000u, 0x07060302u);
}

#define GLD16(g, l) __builtin_amdgcn_global_load_lds((const __attribute__((address_space(1))) void*)(g), (__attribute__((address_space(3))) void*)(l), 16, 0, 0)

// ---------------- fused prep: cast x (1536 blk) | tcast w_qkv (1728 blk) | tcast w_proj (576 blk) ----------------
__global__ __launch_bounds__(256) void k_prep(const float* __restrict__ x, u16* __restrict__ Xb,
                                              const float* __restrict__ wqkv, u16* __restrict__ WqkvT,
                                              const float* __restrict__ wproj, u16* __restrict__ WprojT){
  __shared__ float t[32][33];
  const int bid = blockIdx.x, tid = threadIdx.x;
  if (bid < 1536){
    int i = bid * 256 + tid;
    const f32x4* p = (const f32x4*)(x + (size_t)i * 8);
    f32x4 a = p[0], b = p[1];
    u16 h[8];
#pragma unroll
    for (int j = 0; j < 4; ++j){ h[j] = f2b(a[j]); h[4+j] = f2b(b[j]); }
    *(bf16x8*)(Xb + (size_t)i * 8) = *(const bf16x8*)h;
    return;
  }
  const float* in; u16* out; int R, C, bx, by;
  if (bid < 1536 + 1728){
    int q = bid - 1536; in = wqkv; out = WqkvT; R = 768; C = 2304; bx = q % 72; by = q / 72;
  } else {
    int q = bid - 1536 - 1728; in = wproj; out = WprojT; R = 768; C = 768; bx = q % 24; by = q / 24;
  }
  int c0 = bx * 32, r0 = by * 32;
  int tx = tid & 31, ty = tid >> 5;
#pragma unroll
  for (int i = 0; i < 32; i += 8) t[ty + i][tx] = in[(size_t)(r0 + ty + i) * C + c0 + tx];
  __syncthreads();
#pragma unroll
  for (int i = 0; i < 32; i += 8) out[(size_t)(c0 + ty + i) * R + r0 + tx] = f2b(t[tx][ty + i]);
}

// ---------------- QKV GEMM: 128x96 tile, grid 32x24 = 768 blocks (3.0/CU) ----------------
__global__ __launch_bounds__(256) void k_gemmqkv(const u16* __restrict__ A, const u16* __restrict__ Bt,
                                                 u16* __restrict__ Qp, u16* __restrict__ Kp, u16* __restrict__ Vtp){
  __shared__ __align__(16) u16 SM[14336];
  u16* Al = SM; u16* Bl = SM + 8192;
  const int tid = threadIdx.x;
  const int w = tid >> 6, l = tid & 63;
  const int m0 = blockIdx.x * 128, n0 = blockIdx.y * 96;
  const int wm = (w >> 1) * 64, wn = (w & 1) * 48;
  const int lg = l >> 4, lr = l & 15;
  f32x4 acc[4][3] = {};
  const u16* asrc = A  + (size_t)(m0 + w*32 + (l >> 3)) * 768 + (l & 7) * 8;
  const u16* bsrc = Bt + (size_t)(n0 + w*24 + (l >> 3)) * 768 + (l & 7) * 8;
  for (int k0 = 0; k0 < 768; k0 += 64){
#pragma unroll
    for (int i = 0; i < 4; ++i)
      GLD16(asrc + (size_t)(i*8)*768 + k0, &Al[(w*32 + i*8) * 64]);
#pragma unroll
    for (int i = 0; i < 3; ++i)
      GLD16(bsrc + (size_t)(i*8)*768 + k0, &Bl[(w*24 + i*8) * 64]);
    __syncthreads();
    bf16x8 af[4][2], bfr[3][2];
#pragma unroll
    for (int mf = 0; mf < 4; ++mf)
#pragma unroll
      for (int ks = 0; ks < 2; ++ks)
        af[mf][ks] = *(const bf16x8*)&Al[(wm + mf*16 + lr) * 64 + ks*32 + lg*8];
#pragma unroll
    for (int nf = 0; nf < 3; ++nf)
#pragma unroll
      for (int ks = 0; ks < 2; ++ks)
        bfr[nf][ks] = *(const bf16x8*)&Bl[(wn + nf*16 + lr) * 64 + ks*32 + lg*8];
#pragma unroll
    for (int ks = 0; ks < 2; ++ks)
#pragma unroll
      for (int mf = 0; mf < 4; ++mf)
#pragma unroll
        for (int nf = 0; nf < 3; ++nf)
          acc[mf][nf] = __builtin_amdgcn_mfma_f32_16x16x32_bf16(af[mf][ks], bfr[nf][ks], acc[mf][nf], 0, 0, 0);
    __syncthreads();
  }

  const int which = n0 / 768;
  const int nl0 = n0 - which * 768;
  if (which < 2){
    u16* dst = (which == 0) ? Qp : Kp;
    const float sc = (which == 0) ? 0.125f * LOG2E : 1.0f;
#pragma unroll
    for (int mf = 0; mf < 4; ++mf)
#pragma unroll
      for (int nf = 0; nf < 3; ++nf)
#pragma unroll
        for (int r = 0; r < 4; ++r){
          int m = m0 + wm + mf*16 + lg*4 + r;
          int n = nl0 + wn + nf*16 + lr;
          int b = m >> 11, row = m & 2047, hh = n >> 6, d = n & 63;
          dst[(size_t)((b*12 + hh)*2048 + row) * 64 + d] = f2b(acc[mf][nf][r] * sc);
        }
  } else {
#pragma unroll
    for (int mf = 0; mf < 4; ++mf)
#pragma unroll
      for (int nf = 0; nf < 3; ++nf)
#pragma unroll
        for (int r = 0; r < 4; ++r){
          int mrow = wm + mf*16 + lg*4 + r;
          int c    = wn + nf*16 + lr;
          SM[c * 128 + mrow] = f2b(acc[mf][nf][r]);
        }
    __syncthreads();
#pragma unroll
    for (int rr = 0; rr < 6; ++rr){
      int c  = rr*16 + (tid >> 4);
      int mo = (tid & 15) * 8;
      bf16x8 v = *(const bf16x8*)&SM[c * 128 + mo];
      int n = nl0 + c, hh = n >> 6, d = n & 63;
      int m = m0 + mo, b = m >> 11, key = m & 2047;
      *(bf16x8*)&Vtp[(size_t)((b*12 + hh)*64 + d) * 2048 + key] = v;
    }
  }
}

// ---------------- proj GEMM: 64x64 tile, grid 64x12 = 768 blocks (3.0/CU) ----------------
__global__ __launch_bounds__(256) void k_gemm64(const u16* __restrict__ A, const u16* __restrict__ Bt,
                                                float* __restrict__ Co){
  __shared__ __align__(16) u16 SM[8192];
  u16* Al = SM; u16* Bl = SM + 4096;
  const int tid = threadIdx.x;
  const int w = tid >> 6, l = tid & 63;
  const int m0 = blockIdx.x * 64, n0 = blockIdx.y * 64;
  const int wm = (w >> 1) * 32, wn = (w & 1) * 32;
  const int lg = l >> 4, lr = l & 15;
  f32x4 acc[2][2] = {};
  const u16* asrc = A  + (size_t)(m0 + w*16 + (l >> 3)) * 768 + (l & 7) * 8;
  const u16* bsrc = Bt + (size_t)(n0 + w*16 + (l >> 3)) * 768 + (l & 7) * 8;
  for (int k0 = 0; k0 < 768; k0 += 64){
#pragma unroll
    for (int i = 0; i < 2; ++i){
      GLD16(asrc + (size_t)(i*8)*768 + k0, &Al[(w*16 + i*8) * 64]);
      GLD16(bsrc + (size_t)(i*8)*768 + k0, &Bl[(w*16 + i*8) * 64]);
    }
    __syncthreads();
    bf16x8 af[2][2], bfr[2][2];
#pragma unroll
    for (int mf = 0; mf < 2; ++mf)
#pragma unroll
      for (int ks = 0; ks < 2; ++ks){
        af[mf][ks]  = *(const bf16x8*)&Al[(wm + mf*16 + lr) * 64 + ks*32 + lg*8];
        bfr[mf][ks] = *(const bf16x8*)&Bl[(wn + mf*16 + lr) * 64 + ks*32 + lg*8];
      }
#pragma unroll
    for (int ks = 0; ks < 2; ++ks)
#pragma unroll
      for (int mf = 0; mf < 2; ++mf)
#pragma unroll
        for (int nf = 0; nf < 2; ++nf)
          acc[mf][nf] = __builtin_amdgcn_mfma_f32_16x16x32_bf16(af[mf][ks], bfr[nf][ks], acc[mf][nf], 0, 0, 0);  // bfr[nf] (r9 fix, keep)
    __syncthreads();
  }
#pragma unroll
  for (int mf = 0; mf < 2; ++mf)
#pragma unroll
    for (int nf = 0; nf < 2; ++nf)
#pragma unroll
      for (int r = 0; r < 4; ++r)
        Co[(size_t)(m0 + wm + mf*16 + lg*4 + r) * 768 + n0 + wn + nf*16 + lr] = acc[mf][nf][r];
}

// ---------------- flash attention: 8-wave, K-staged-only, V direct from L2, XCD-swizzled ----------------
// r18: LDS was the top pipe (~71%). (1) V is NOT staged: PV A-fragments load directly from global
// Vt (L2-resident thanks to the swizzle). (2) Bijective XCD swizzle: each XCD's 96 co-resident
// blocks share 3 bh -> K/V served from its private 4MB L2 (r14: FETCH 52->9.3 MB). (3) K-only
// 3-buffer counted-vmcnt(1) pipeline; LDS 48->24 KB. ORDER: V loads are issued BEFORE the K
// prefetch, so the compiler's auto-wait for V is vmcnt(1) and never drains the K prefetch.
__global__ __launch_bounds__(512, 6) void k_attn(const u16* __restrict__ Qp, const u16* __restrict__ Kp,
                                                 const u16* __restrict__ Vtp, u16* __restrict__ AO){
  __shared__ __align__(16) u16 SM[12288];        // 24 KB: K 3x4096 u16; epilogue f32 scratch (16.9KB) reuses
  const int tid = threadIdx.x, w = tid >> 6, l = tid & 63;
  const int QH = w >> 1, KH = w & 1;
  const int lg = l >> 4, lr = l & 15;
  const int p = blockIdx.x;
  const int lgid = ((p & 7) * 96) + (p >> 3);    // bijective XCD swizzle (768 % 8 == 0)
  const int qt_b = lgid & 31, bh = lgid >> 5;
  const int b = bh / 12, hh = bh - b * 12;
  const size_t base = (size_t)bh * (2048 * 64);
  const u16* Qg = Qp + base; const u16* Kg = Kp + base; const u16* Vg = Vtp + base;
  const int q0w = qt_b * 64 + QH * 16;
  const int rsw = (lr & 7) * 8;                  // read-side XOR (K only)

  // Q B-fragments: qf[ks]: q = q0w + lr, d = ks*32 + lg*8 + j
  bf16x8 qf[2];
#pragma unroll
  for (int ks = 0; ks < 2; ++ks)
    qf[ks] = *(const bf16x8*)&Qg[(size_t)(q0w + lr) * 64 + ks*32 + lg*8];

  f32x4 oacc[4] = {};                            // [nf]: O[d=nf*16+lg*4+r][q=lr] (key-half partial)
  float lp = 0.f;

  // K staging: 512 threads x 1 GLD16 cover the 64x64 u16 K tile.
  // dest row p_ = tid>>3, col octet tid&7; T21 source col16 = (tid&7)^(p_&7).
  // K source rows permuted: srckey(p_) = 32*(p_>>5) + 8*((p_>>2)&3) + 4*((p_>>4)&1) + (p_&3).
  const int p_  = tid >> 3;
  const int sk  = 32*(p_ >> 5) + 8*((p_ >> 2) & 3) + 4*((p_ >> 4) & 1) + (p_ & 3);
  const int cs8 = (((tid & 7) ^ (p_ & 7)) << 3);
  const u16* kp = Kg + (size_t)sk * 64 + cs8;    // induction: += 4096 per tile
  const int drow = p_ * 64;
  u16* const K0 = SM + 0    + drow;
  u16* const K1 = SM + 4096 + drow;
  u16* const K2 = SM + 8192 + drow;

  // V direct-from-global pointer: row d = nf*16 + lr (offset nf*32768), col = k0 + KH*32 + lg*8
  const u16* vp = Vg + (size_t)lr * 2048 + KH*32 + lg*8;   // induction: += 64 per tile

  auto compute = [&](const u16* Kc, const bf16x8* vfr){
    f32x4 s[2] = {};                             // s[kf]: C col=lr=q, row=kf*16+4lg+r -> key 8lg+4kf+r
    bf16x8 kfr[2][2];
#pragma unroll
    for (int kf = 0; kf < 2; ++kf)
#pragma unroll
      for (int ks = 0; ks < 2; ++ks)
        kfr[kf][ks] = *(const bf16x8*)&Kc[(KH*32 + kf*16 + lr) * 64 + ((ks*32 + lg*8) ^ rsw)];
    __builtin_amdgcn_s_setprio(1);
#pragma unroll
    for (int ks = 0; ks < 2; ++ks)
#pragma unroll
      for (int kf = 0; kf < 2; ++kf)
        s[kf] = __builtin_amdgcn_mfma_f32_16x16x32_bf16(kfr[kf][ks], qf[ks], s[kf], 0, 0, 0);
    __builtin_amdgcn_s_setprio(0);

    // P = exp2(S'); B-frag slot j: j=0..3 from s[0], j=4..7 from s[1] (key = KH*32 + 8lg + j)
    float p00 = __builtin_exp2f(s[0][0]);
    float p01 = __builtin_exp2f(s[0][1]);
    float p02 = __builtin_exp2f(s[0][2]);
    float p03 = __builtin_exp2f(s[0][3]);
    float p10 = __builtin_exp2f(s[1][0]);
    float p11 = __builtin_exp2f(s[1][1]);
    float p12 = __builtin_exp2f(s[1][2]);
    float p13 = __builtin_exp2f(s[1][3]);
    lp += ((p00 + p01) + (p02 + p03)) + ((p10 + p11) + (p12 + p13));
    union { uint32_t u[4]; bf16x8 v; } fr;
    fr.u[0] = pkrhu(p00, p01);
    fr.u[1] = pkrhu(p02, p03);
    fr.u[2] = pkrhu(p10, p11);
    fr.u[3] = pkrhu(p12, p13);

    __builtin_amdgcn_s_setprio(1);
#pragma unroll
    for (int nf = 0; nf < 4; ++nf)
      oacc[nf] = __builtin_amdgcn_mfma_f32_16x16x32_bf16(vfr[nf], fr.v, oacc[nf], 0, 0, 0);
    __builtin_amdgcn_s_setprio(0);
  };

#define VLOAD(VF) do { _Pragma("unroll") \
    for (int nf = 0; nf < 4; ++nf) VF[nf] = *(const bf16x8*)(vp + (size_t)nf * 32768); \
    vp += 64; } while(0)
#define STAGE1(KD) do { GLD16(kp, KD); kp += 4096; } while(0)
#define BAR_CNT1  do { asm volatile("s_waitcnt vmcnt(1)" ::: "memory"); \
                       __builtin_amdgcn_s_barrier(); __builtin_amdgcn_sched_barrier(0); } while(0)
#define BAR_CNT0  do { asm volatile("s_waitcnt vmcnt(0)" ::: "memory"); \
                       __builtin_amdgcn_s_barrier(); __builtin_amdgcn_sched_barrier(0); } while(0)

  // prologue: stage K t0->buf0, t1->buf1; ensure t0 landed (t1's load may remain in flight)
  STAGE1(K0);
  STAGE1(K1);
  BAR_CNT1;

  bf16x8 vfr[4];
  for (int g = 0; g < 10; ++g){
    VLOAD(vfr); STAGE1(K2); compute(SM + 0,    vfr); BAR_CNT1;   // t=3g
    VLOAD(vfr); STAGE1(K0); compute(SM + 4096, vfr); BAR_CNT1;   // t=3g+1
    VLOAD(vfr); STAGE1(K1); compute(SM + 8192, vfr); BAR_CNT1;   // t=3g+2
  }
  VLOAD(vfr); compute(SM + 0,    vfr);   // t=30 (no prefetch)
  BAR_CNT0;                              // ensure K t=31 landed
  VLOAD(vfr); compute(SM + 4096, vfr);   // t=31

#undef VLOAD
#undef STAGE1
#undef BAR_CNT1
#undef BAR_CNT0

  // per-q row sum over this wave's key half (q = lr; reduce over lg lanes)
  float lt = lp;
  lt += __shfl_xor(lt, 16);
  lt += __shfl_xor(lt, 32);

  __syncthreads();   // full sync before reusing SM as f32 scratch
  // split-key merge (pure sums under no-max): KH=1 publishes, KH=0 merges + stores.
  float* Osc = (float*)SM;                        // [64 q][65] f32 (stride 65, conflict-free) = 16640 B
  float* Lsc = Osc + 64 * 65;                     // [64 q] f32  (total 16896 B <= 24576 B)
  if (KH == 1){
#pragma unroll
    for (int nf = 0; nf < 4; ++nf)
#pragma unroll
      for (int r = 0; r < 4; ++r)
        Osc[(QH*16 + lr) * 65 + nf*16 + lg*4 + r] = oacc[nf][r];
    if (lg == 0) Lsc[QH*16 + lr] = lt;
  }
  __syncthreads();
  if (KH == 0){
    float inv = 1.0f / (lt + Lsc[QH*16 + lr]);
#pragma unroll
    for (int nf = 0; nf < 4; ++nf)
#pragma unroll
      for (int r = 0; r < 4; ++r){
        float o = oacc[nf][r] + Osc[(QH*16 + lr) * 65 + nf*16 + lg*4 + r];
        AO[(size_t)((b << 11) + q0w + lr) * 768 + hh*64 + nf*16 + lg*4 + r] = f2b(o * inv);
      }
  }
}

extern "C" void kernel_launch(void* const* d_in, const int* in_sizes, int n_in,
                              void* d_out, int out_size, void* d_ws, size_t ws_size,
                              hipStream_t stream){
  const float* x      = (const float*)d_in[0];
  const float* w_qkv  = (const float*)d_in[1];
  const float* w_proj = (const float*)d_in[2];
  float* out = (float*)d_out;
  char* ws = (char*)d_ws;
  u16* Xb     = (u16*)(ws + 0);
  u16* WqkvT  = (u16*)(ws + 6291456);
  u16* WprojT = (u16*)(ws + 9830400);
  u16* Qp     = (u16*)(ws + 11010048);
  u16* Kp     = (u16*)(ws + 17301504);
  u16* Vtp    = (u16*)(ws + 23592960);
  u16* AO     = (u16*)(ws + 29884416);

  k_prep<<<3840, 256, 0, stream>>>(x, Xb, w_qkv, WqkvT, w_proj, WprojT);
  k_gemmqkv<<<dim3(32, 24), 256, 0, stream>>>(Xb, WqkvT, Qp, Kp, Vtp);
  k_attn<<<768, 512, 0, stream>>>(Qp, Kp, Vtp, AO);
  k_gemm64<<<dim3(64, 12), 256, 0, stream>>>(AO, WprojT, out);
}

// Round 19
// 206.569 us; speedup vs baseline: 1.0291x; 1.0291x over previous
//
#include <hip/hip_runtime.h>
#include <hip/hip_bf16.h>
#include <stdint.h>

typedef uint16_t u16;
typedef __attribute__((ext_vector_type(4))) float f32x4;
typedef __attribute__((ext_vector_type(8))) short bf16x8;

#define LOG2E 1.4426950408889634f

static __device__ __forceinline__ u16 f2b(float x){
  union { float f; uint32_t u; } a; a.f = x;
  uint32_t r = a.u + 0x7FFFu + ((a.u >> 16) & 1u);
  return (u16)(r >> 16);
}

// pack two f32 -> two bf16 (round-half-up) in 3 VALU: add, add, v_perm_b32
static __device__ __forceinline__ uint32_t pkrhu(float lo, float hi){
  union { float f; uint32_t u; } a, b; a.f = lo; b.f = hi;
  return __builtin_amdgcn_perm(b.u + 0x8000u, a.u + 0x8000u, 0x07060302u);
}

#define GLD16(g, l) __builtin_amdgcn_global_load_lds((const __attribute__((address_space(1))) void*)(g), (__attribute__((address_space(3))) void*)(l), 16, 0, 0)

// ---------------- fused prep: cast x (1536 blk) | tcast w_qkv (1728 blk) | tcast w_proj (576 blk) ----------------
__global__ __launch_bounds__(256) void k_prep(const float* __restrict__ x, u16* __restrict__ Xb,
                                              const float* __restrict__ wqkv, u16* __restrict__ WqkvT,
                                              const float* __restrict__ wproj, u16* __restrict__ WprojT){
  __shared__ float t[32][33];
  const int bid = blockIdx.x, tid = threadIdx.x;
  if (bid < 1536){
    int i = bid * 256 + tid;
    const f32x4* p = (const f32x4*)(x + (size_t)i * 8);
    f32x4 a = p[0], b = p[1];
    u16 h[8];
#pragma unroll
    for (int j = 0; j < 4; ++j){ h[j] = f2b(a[j]); h[4+j] = f2b(b[j]); }
    *(bf16x8*)(Xb + (size_t)i * 8) = *(const bf16x8*)h;
    return;
  }
  const float* in; u16* out; int R, C, bx, by;
  if (bid < 1536 + 1728){
    int q = bid - 1536; in = wqkv; out = WqkvT; R = 768; C = 2304; bx = q % 72; by = q / 72;
  } else {
    int q = bid - 1536 - 1728; in = wproj; out = WprojT; R = 768; C = 768; bx = q % 24; by = q / 24;
  }
  int c0 = bx * 32, r0 = by * 32;
  int tx = tid & 31, ty = tid >> 5;
#pragma unroll
  for (int i = 0; i < 32; i += 8) t[ty + i][tx] = in[(size_t)(r0 + ty + i) * C + c0 + tx];
  __syncthreads();
#pragma unroll
  for (int i = 0; i < 32; i += 8) out[(size_t)(c0 + ty + i) * R + r0 + tx] = f2b(t[tx][ty + i]);
}

// ---------------- QKV GEMM: 128x96 tile, grid 32x24 = 768 blocks (3.0/CU) ----------------
__global__ __launch_bounds__(256) void k_gemmqkv(const u16* __restrict__ A, const u16* __restrict__ Bt,
                                                 u16* __restrict__ Qp, u16* __restrict__ Kp, u16* __restrict__ Vtp){
  __shared__ __align__(16) u16 SM[14336];
  u16* Al = SM; u16* Bl = SM + 8192;
  const int tid = threadIdx.x;
  const int w = tid >> 6, l = tid & 63;
  const int m0 = blockIdx.x * 128, n0 = blockIdx.y * 96;
  const int wm = (w >> 1) * 64, wn = (w & 1) * 48;
  const int lg = l >> 4, lr = l & 15;
  f32x4 acc[4][3] = {};
  const u16* asrc = A  + (size_t)(m0 + w*32 + (l >> 3)) * 768 + (l & 7) * 8;
  const u16* bsrc = Bt + (size_t)(n0 + w*24 + (l >> 3)) * 768 + (l & 7) * 8;
  for (int k0 = 0; k0 < 768; k0 += 64){
#pragma unroll
    for (int i = 0; i < 4; ++i)
      GLD16(asrc + (size_t)(i*8)*768 + k0, &Al[(w*32 + i*8) * 64]);
#pragma unroll
    for (int i = 0; i < 3; ++i)
      GLD16(bsrc + (size_t)(i*8)*768 + k0, &Bl[(w*24 + i*8) * 64]);
    __syncthreads();
    bf16x8 af[4][2], bfr[3][2];
#pragma unroll
    for (int mf = 0; mf < 4; ++mf)
#pragma unroll
      for (int ks = 0; ks < 2; ++ks)
        af[mf][ks] = *(const bf16x8*)&Al[(wm + mf*16 + lr) * 64 + ks*32 + lg*8];
#pragma unroll
    for (int nf = 0; nf < 3; ++nf)
#pragma unroll
      for (int ks = 0; ks < 2; ++ks)
        bfr[nf][ks] = *(const bf16x8*)&Bl[(wn + nf*16 + lr) * 64 + ks*32 + lg*8];
#pragma unroll
    for (int ks = 0; ks < 2; ++ks)
#pragma unroll
      for (int mf = 0; mf < 4; ++mf)
#pragma unroll
        for (int nf = 0; nf < 3; ++nf)
          acc[mf][nf] = __builtin_amdgcn_mfma_f32_16x16x32_bf16(af[mf][ks], bfr[nf][ks], acc[mf][nf], 0, 0, 0);
    __syncthreads();
  }

  const int which = n0 / 768;
  const int nl0 = n0 - which * 768;
  if (which < 2){
    u16* dst = (which == 0) ? Qp : Kp;
    const float sc = (which == 0) ? 0.125f * LOG2E : 1.0f;
#pragma unroll
    for (int mf = 0; mf < 4; ++mf)
#pragma unroll
      for (int nf = 0; nf < 3; ++nf)
#pragma unroll
        for (int r = 0; r < 4; ++r){
          int m = m0 + wm + mf*16 + lg*4 + r;
          int n = nl0 + wn + nf*16 + lr;
          int b = m >> 11, row = m & 2047, hh = n >> 6, d = n & 63;
          dst[(size_t)((b*12 + hh)*2048 + row) * 64 + d] = f2b(acc[mf][nf][r] * sc);
        }
  } else {
#pragma unroll
    for (int mf = 0; mf < 4; ++mf)
#pragma unroll
      for (int nf = 0; nf < 3; ++nf)
#pragma unroll
        for (int r = 0; r < 4; ++r){
          int mrow = wm + mf*16 + lg*4 + r;
          int c    = wn + nf*16 + lr;
          SM[c * 128 + mrow] = f2b(acc[mf][nf][r]);
        }
    __syncthreads();
#pragma unroll
    for (int rr = 0; rr < 6; ++rr){
      int c  = rr*16 + (tid >> 4);
      int mo = (tid & 15) * 8;
      bf16x8 v = *(const bf16x8*)&SM[c * 128 + mo];
      int n = nl0 + c, hh = n >> 6, d = n & 63;
      int m = m0 + mo, b = m >> 11, key = m & 2047;
      *(bf16x8*)&Vtp[(size_t)((b*12 + hh)*64 + d) * 2048 + key] = v;
    }
  }
}

// ---------------- proj GEMM: 64x64 tile, grid 64x12 = 768 blocks (3.0/CU) ----------------
__global__ __launch_bounds__(256) void k_gemm64(const u16* __restrict__ A, const u16* __restrict__ Bt,
                                                float* __restrict__ Co){
  __shared__ __align__(16) u16 SM[8192];
  u16* Al = SM; u16* Bl = SM + 4096;
  const int tid = threadIdx.x;
  const int w = tid >> 6, l = tid & 63;
  const int m0 = blockIdx.x * 64, n0 = blockIdx.y * 64;
  const int wm = (w >> 1) * 32, wn = (w & 1) * 32;
  const int lg = l >> 4, lr = l & 15;
  f32x4 acc[2][2] = {};
  const u16* asrc = A  + (size_t)(m0 + w*16 + (l >> 3)) * 768 + (l & 7) * 8;
  const u16* bsrc = Bt + (size_t)(n0 + w*16 + (l >> 3)) * 768 + (l & 7) * 8;
  for (int k0 = 0; k0 < 768; k0 += 64){
#pragma unroll
    for (int i = 0; i < 2; ++i){
      GLD16(asrc + (size_t)(i*8)*768 + k0, &Al[(w*16 + i*8) * 64]);
      GLD16(bsrc + (size_t)(i*8)*768 + k0, &Bl[(w*16 + i*8) * 64]);
    }
    __syncthreads();
    bf16x8 af[2][2], bfr[2][2];
#pragma unroll
    for (int mf = 0; mf < 2; ++mf)
#pragma unroll
      for (int ks = 0; ks < 2; ++ks){
        af[mf][ks]  = *(const bf16x8*)&Al[(wm + mf*16 + lr) * 64 + ks*32 + lg*8];
        bfr[mf][ks] = *(const bf16x8*)&Bl[(wn + mf*16 + lr) * 64 + ks*32 + lg*8];
      }
#pragma unroll
    for (int ks = 0; ks < 2; ++ks)
#pragma unroll
      for (int mf = 0; mf < 2; ++mf)
#pragma unroll
        for (int nf = 0; nf < 2; ++nf)
          acc[mf][nf] = __builtin_amdgcn_mfma_f32_16x16x32_bf16(af[mf][ks], bfr[nf][ks], acc[mf][nf], 0, 0, 0);  // bfr[nf] (r9 fix, keep)
    __syncthreads();
  }
#pragma unroll
  for (int mf = 0; mf < 2; ++mf)
#pragma unroll
    for (int nf = 0; nf < 2; ++nf)
#pragma unroll
      for (int r = 0; r < 4; ++r)
        Co[(size_t)(m0 + wm + mf*16 + lg*4 + r) * 768 + n0 + wn + nf*16 + lr] = acc[mf][nf][r];
}

// ---------------- flash attention: 8-wave, K-staged-only, V direct from L2, XCD-swizzled ----------------
// r19: r18's V-direct structure with the SCRATCH BUG fixed. r18 passed vfr[] as a POINTER into the
// compute lambda -> local array demoted to scratch -> 297 MB HBM writes (WRITE_SIZE counter) and 185 µs.
// Now V fragments are 4 NAMED registers passed BY VALUE (no arrays, no pointers -> stays in VGPRs).
// K-only 3-buffer counted-vmcnt(1) pipeline; bijective XCD swizzle keeps each XCD's 3-bh K/V slice
// (1.5 MB) resident in its private L2 so the per-step direct V loads are L2-hits.
__global__ __launch_bounds__(512, 6) void k_attn(const u16* __restrict__ Qp, const u16* __restrict__ Kp,
                                                 const u16* __restrict__ Vtp, u16* __restrict__ AO){
  __shared__ __align__(16) u16 SM[12288];        // 24 KB: K 3x4096 u16; epilogue f32 scratch (16.9KB) reuses
  const int tid = threadIdx.x, w = tid >> 6, l = tid & 63;
  const int QH = w >> 1, KH = w & 1;
  const int lg = l >> 4, lr = l & 15;
  const int p = blockIdx.x;
  const int lgid = ((p & 7) * 96) + (p >> 3);    // bijective XCD swizzle (768 % 8 == 0)
  const int qt_b = lgid & 31, bh = lgid >> 5;
  const int b = bh / 12, hh = bh - b * 12;
  const size_t base = (size_t)bh * (2048 * 64);
  const u16* Qg = Qp + base; const u16* Kg = Kp + base; const u16* Vg = Vtp + base;
  const int q0w = qt_b * 64 + QH * 16;
  const int rsw = (lr & 7) * 8;                  // read-side XOR (K only)

  // Q B-fragments: qf[ks]: q = q0w + lr, d = ks*32 + lg*8 + j
  bf16x8 qf[2];
#pragma unroll
  for (int ks = 0; ks < 2; ++ks)
    qf[ks] = *(const bf16x8*)&Qg[(size_t)(q0w + lr) * 64 + ks*32 + lg*8];

  f32x4 oacc[4] = {};                            // [nf]: O[d=nf*16+lg*4+r][q=lr] (key-half partial)
  float lp = 0.f;

  // K staging: 512 threads x 1 GLD16 cover the 64x64 u16 K tile.
  // dest row p_ = tid>>3, col octet tid&7; T21 source col16 = (tid&7)^(p_&7).
  // K source rows permuted: srckey(p_) = 32*(p_>>5) + 8*((p_>>2)&3) + 4*((p_>>4)&1) + (p_&3).
  const int p_  = tid >> 3;
  const int sk  = 32*(p_ >> 5) + 8*((p_ >> 2) & 3) + 4*((p_ >> 4) & 1) + (p_ & 3);
  const int cs8 = (((tid & 7) ^ (p_ & 7)) << 3);
  const u16* kp = Kg + (size_t)sk * 64 + cs8;    // induction: += 4096 per tile
  const int drow = p_ * 64;
  u16* const K0 = SM + 0    + drow;
  u16* const K1 = SM + 4096 + drow;
  u16* const K2 = SM + 8192 + drow;

  // V direct-from-global pointer: row d = nf*16 + lr (offset nf*32768), col = k0 + KH*32 + lg*8
  const u16* vp = Vg + (size_t)lr * 2048 + KH*32 + lg*8;   // induction: += 64 per tile

  auto compute = [&](const u16* Kc, bf16x8 vf0, bf16x8 vf1, bf16x8 vf2, bf16x8 vf3){
    f32x4 s[2] = {};                             // s[kf]: C col=lr=q, row=kf*16+4lg+r -> key 8lg+4kf+r
    bf16x8 kfr[2][2];
#pragma unroll
    for (int kf = 0; kf < 2; ++kf)
#pragma unroll
      for (int ks = 0; ks < 2; ++ks)
        kfr[kf][ks] = *(const bf16x8*)&Kc[(KH*32 + kf*16 + lr) * 64 + ((ks*32 + lg*8) ^ rsw)];
    __builtin_amdgcn_s_setprio(1);
#pragma unroll
    for (int ks = 0; ks < 2; ++ks)
#pragma unroll
      for (int kf = 0; kf < 2; ++kf)
        s[kf] = __builtin_amdgcn_mfma_f32_16x16x32_bf16(kfr[kf][ks], qf[ks], s[kf], 0, 0, 0);
    __builtin_amdgcn_s_setprio(0);

    // P = exp2(S'); B-frag slot j: j=0..3 from s[0], j=4..7 from s[1] (key = KH*32 + 8lg + j)
    float p00 = __builtin_exp2f(s[0][0]);
    float p01 = __builtin_exp2f(s[0][1]);
    float p02 = __builtin_exp2f(s[0][2]);
    float p03 = __builtin_exp2f(s[0][3]);
    float p10 = __builtin_exp2f(s[1][0]);
    float p11 = __builtin_exp2f(s[1][1]);
    float p12 = __builtin_exp2f(s[1][2]);
    float p13 = __builtin_exp2f(s[1][3]);
    lp += ((p00 + p01) + (p02 + p03)) + ((p10 + p11) + (p12 + p13));
    union { uint32_t u[4]; bf16x8 v; } fr;
    fr.u[0] = pkrhu(p00, p01);
    fr.u[1] = pkrhu(p02, p03);
    fr.u[2] = pkrhu(p10, p11);
    fr.u[3] = pkrhu(p12, p13);

    __builtin_amdgcn_s_setprio(1);
    oacc[0] = __builtin_amdgcn_mfma_f32_16x16x32_bf16(vf0, fr.v, oacc[0], 0, 0, 0);
    oacc[1] = __builtin_amdgcn_mfma_f32_16x16x32_bf16(vf1, fr.v, oacc[1], 0, 0, 0);
    oacc[2] = __builtin_amdgcn_mfma_f32_16x16x32_bf16(vf2, fr.v, oacc[2], 0, 0, 0);
    oacc[3] = __builtin_amdgcn_mfma_f32_16x16x32_bf16(vf3, fr.v, oacc[3], 0, 0, 0);
    __builtin_amdgcn_s_setprio(0);
  };

  // V loads as 4 NAMED registers (by value — never an addressable array)
#define VLOAD4  vf0 = *(const bf16x8*)(vp);            \
                vf1 = *(const bf16x8*)(vp + 32768);    \
                vf2 = *(const bf16x8*)(vp + 65536);    \
                vf3 = *(const bf16x8*)(vp + 98304);    \
                vp += 64
#define STAGE1(KD) do { GLD16(kp, KD); kp += 4096; } while(0)
#define BAR_CNT1  do { asm volatile("s_waitcnt vmcnt(1)" ::: "memory"); \
                       __builtin_amdgcn_s_barrier(); __builtin_amdgcn_sched_barrier(0); } while(0)
#define BAR_CNT0  do { asm volatile("s_waitcnt vmcnt(0)" ::: "memory"); \
                       __builtin_amdgcn_s_barrier(); __builtin_amdgcn_sched_barrier(0); } while(0)

  // prologue: stage K t0->buf0, t1->buf1; ensure t0 landed (t1's load may remain in flight)
  STAGE1(K0);
  STAGE1(K1);
  BAR_CNT1;

  bf16x8 vf0, vf1, vf2, vf3;
  for (int g = 0; g < 10; ++g){
    VLOAD4; STAGE1(K2); compute(SM + 0,    vf0, vf1, vf2, vf3); BAR_CNT1;   // t=3g
    VLOAD4; STAGE1(K0); compute(SM + 4096, vf0, vf1, vf2, vf3); BAR_CNT1;   // t=3g+1
    VLOAD4; STAGE1(K1); compute(SM + 8192, vf0, vf1, vf2, vf3); BAR_CNT1;   // t=3g+2
  }
  VLOAD4; compute(SM + 0,    vf0, vf1, vf2, vf3);   // t=30 (no prefetch)
  BAR_CNT0;                                         // ensure K t=31 landed
  VLOAD4; compute(SM + 4096, vf0, vf1, vf2, vf3);   // t=31

#undef VLOAD4
#undef STAGE1
#undef BAR_CNT1
#undef BAR_CNT0

  // per-q row sum over this wave's key half (q = lr; reduce over lg lanes)
  float lt = lp;
  lt += __shfl_xor(lt, 16);
  lt += __shfl_xor(lt, 32);

  __syncthreads();   // full sync before reusing SM as f32 scratch
  // split-key merge (pure sums under no-max): KH=1 publishes, KH=0 merges + stores.
  float* Osc = (float*)SM;                        // [64 q][65] f32 (stride 65, conflict-free) = 16640 B
  float* Lsc = Osc + 64 * 65;                     // [64 q] f32  (total 16896 B <= 24576 B)
  if (KH == 1){
#pragma unroll
    for (int nf = 0; nf < 4; ++nf)
#pragma unroll
      for (int r = 0; r < 4; ++r)
        Osc[(QH*16 + lr) * 65 + nf*16 + lg*4 + r] = oacc[nf][r];
    if (lg == 0) Lsc[QH*16 + lr] = lt;
  }
  __syncthreads();
  if (KH == 0){
    float inv = 1.0f / (lt + Lsc[QH*16 + lr]);
#pragma unroll
    for (int nf = 0; nf < 4; ++nf)
#pragma unroll
      for (int r = 0; r < 4; ++r){
        float o = oacc[nf][r] + Osc[(QH*16 + lr) * 65 + nf*16 + lg*4 + r];
        AO[(size_t)((b << 11) + q0w + lr) * 768 + hh*64 + nf*16 + lg*4 + r] = f2b(o * inv);
      }
  }
}

extern "C" void kernel_launch(void* const* d_in, const int* in_sizes, int n_in,
                              void* d_out, int out_size, void* d_ws, size_t ws_size,
                              hipStream_t stream){
  const float* x      = (const float*)d_in[0];
  const float* w_qkv  = (const float*)d_in[1];
  const float* w_proj = (const float*)d_in[2];
  float* out = (float*)d_out;
  char* ws = (char*)d_ws;
  u16* Xb     = (u16*)(ws + 0);
  u16* WqkvT  = (u16*)(ws + 6291456);
  u16* WprojT = (u16*)(ws + 9830400);
  u16* Qp     = (u16*)(ws + 11010048);
  u16* Kp     = (u16*)(ws + 17301504);
  u16* Vtp    = (u16*)(ws + 23592960);
  u16* AO     = (u16*)(ws + 29884416);

  k_prep<<<3840, 256, 0, stream>>>(x, Xb, w_qkv, WqkvT, w_proj, WprojT);
  k_gemmqkv<<<dim3(32, 24), 256, 0, stream>>>(Xb, WqkvT, Qp, Kp, Vtp);
  k_attn<<<768, 512, 0, stream>>>(Qp, Kp, Vtp, AO);
  k_gemm64<<<dim3(64, 12), 256, 0, stream>>>(AO, WprojT, out);
}

// Round 20
// 153.152 us; speedup vs baseline: 1.3880x; 1.3488x over previous
//
#include <hip/hip_runtime.h>
#include <hip/hip_bf16.h>
#include <stdint.h>

typedef uint16_t u16;
typedef __attribute__((ext_vector_type(4))) float f32x4;
typedef __attribute__((ext_vector_type(8))) short bf16x8;

#define LOG2E 1.4426950408889634f

static __device__ __forceinline__ u16 f2b(float x){
  union { float f; uint32_t u; } a; a.f = x;
  uint32_t r = a.u + 0x7FFFu + ((a.u >> 16) & 1u);
  return (u16)(r >> 16);
}

// pack two f32 -> two bf16 (round-half-up) in 3 VALU: add, add, v_perm_b32
static __device__ __forceinline__ uint32_t pkrhu(float lo, float hi){
  union { float f; uint32_t u; } a, b; a.f = lo; b.f = hi;
  return __builtin_amdgcn_perm(b.u + 0x8000u, a.u + 0x8000u, 0x07060302u);
}

#define GLD16(g, l) __builtin_amdgcn_global_load_lds((const __attribute__((address_space(1))) void*)(g), (__attribute__((address_space(3))) void*)(l), 16, 0, 0)

// ---------------- fused prep: cast x (1536 blk) | tcast w_qkv (1728 blk) | tcast w_proj (576 blk) ----------------
__global__ __launch_bounds__(256) void k_prep(const float* __restrict__ x, u16* __restrict__ Xb,
                                              const float* __restrict__ wqkv, u16* __restrict__ WqkvT,
                                              const float* __restrict__ wproj, u16* __restrict__ WprojT){
  __shared__ float t[32][33];
  const int bid = blockIdx.x, tid = threadIdx.x;
  if (bid < 1536){
    int i = bid * 256 + tid;
    const f32x4* p = (const f32x4*)(x + (size_t)i * 8);
    f32x4 a = p[0], b = p[1];
    u16 h[8];
#pragma unroll
    for (int j = 0; j < 4; ++j){ h[j] = f2b(a[j]); h[4+j] = f2b(b[j]); }
    *(bf16x8*)(Xb + (size_t)i * 8) = *(const bf16x8*)h;
    return;
  }
  const float* in; u16* out; int R, C, bx, by;
  if (bid < 1536 + 1728){
    int q = bid - 1536; in = wqkv; out = WqkvT; R = 768; C = 2304; bx = q % 72; by = q / 72;
  } else {
    int q = bid - 1536 - 1728; in = wproj; out = WprojT; R = 768; C = 768; bx = q % 24; by = q / 24;
  }
  int c0 = bx * 32, r0 = by * 32;
  int tx = tid & 31, ty = tid >> 5;
#pragma unroll
  for (int i = 0; i < 32; i += 8) t[ty + i][tx] = in[(size_t)(r0 + ty + i) * C + c0 + tx];
  __syncthreads();
#pragma unroll
  for (int i = 0; i < 32; i += 8) out[(size_t)(c0 + ty + i) * R + r0 + tx] = f2b(t[tx][ty + i]);
}

// ---------------- QKV GEMM: 128x96 tile, grid 32x24 = 768 blocks (3.0/CU) ----------------
__global__ __launch_bounds__(256) void k_gemmqkv(const u16* __restrict__ A, const u16* __restrict__ Bt,
                                                 u16* __restrict__ Qp, u16* __restrict__ Kp, u16* __restrict__ Vtp){
  __shared__ __align__(16) u16 SM[14336];
  u16* Al = SM; u16* Bl = SM + 8192;
  const int tid = threadIdx.x;
  const int w = tid >> 6, l = tid & 63;
  const int m0 = blockIdx.x * 128, n0 = blockIdx.y * 96;
  const int wm = (w >> 1) * 64, wn = (w & 1) * 48;
  const int lg = l >> 4, lr = l & 15;
  f32x4 acc[4][3] = {};
  const u16* asrc = A  + (size_t)(m0 + w*32 + (l >> 3)) * 768 + (l & 7) * 8;
  const u16* bsrc = Bt + (size_t)(n0 + w*24 + (l >> 3)) * 768 + (l & 7) * 8;
  for (int k0 = 0; k0 < 768; k0 += 64){
#pragma unroll
    for (int i = 0; i < 4; ++i)
      GLD16(asrc + (size_t)(i*8)*768 + k0, &Al[(w*32 + i*8) * 64]);
#pragma unroll
    for (int i = 0; i < 3; ++i)
      GLD16(bsrc + (size_t)(i*8)*768 + k0, &Bl[(w*24 + i*8) * 64]);
    __syncthreads();
    bf16x8 af[4][2], bfr[3][2];
#pragma unroll
    for (int mf = 0; mf < 4; ++mf)
#pragma unroll
      for (int ks = 0; ks < 2; ++ks)
        af[mf][ks] = *(const bf16x8*)&Al[(wm + mf*16 + lr) * 64 + ks*32 + lg*8];
#pragma unroll
    for (int nf = 0; nf < 3; ++nf)
#pragma unroll
      for (int ks = 0; ks < 2; ++ks)
        bfr[nf][ks] = *(const bf16x8*)&Bl[(wn + nf*16 + lr) * 64 + ks*32 + lg*8];
#pragma unroll
    for (int ks = 0; ks < 2; ++ks)
#pragma unroll
      for (int mf = 0; mf < 4; ++mf)
#pragma unroll
        for (int nf = 0; nf < 3; ++nf)
          acc[mf][nf] = __builtin_amdgcn_mfma_f32_16x16x32_bf16(af[mf][ks], bfr[nf][ks], acc[mf][nf], 0, 0, 0);
    __syncthreads();
  }

  const int which = n0 / 768;
  const int nl0 = n0 - which * 768;
  if (which < 2){
    u16* dst = (which == 0) ? Qp : Kp;
    const float sc = (which == 0) ? 0.125f * LOG2E : 1.0f;
#pragma unroll
    for (int mf = 0; mf < 4; ++mf)
#pragma unroll
      for (int nf = 0; nf < 3; ++nf)
#pragma unroll
        for (int r = 0; r < 4; ++r){
          int m = m0 + wm + mf*16 + lg*4 + r;
          int n = nl0 + wn + nf*16 + lr;
          int b = m >> 11, row = m & 2047, hh = n >> 6, d = n & 63;
          dst[(size_t)((b*12 + hh)*2048 + row) * 64 + d] = f2b(acc[mf][nf][r] * sc);
        }
  } else {
#pragma unroll
    for (int mf = 0; mf < 4; ++mf)
#pragma unroll
      for (int nf = 0; nf < 3; ++nf)
#pragma unroll
        for (int r = 0; r < 4; ++r){
          int mrow = wm + mf*16 + lg*4 + r;
          int c    = wn + nf*16 + lr;
          SM[c * 128 + mrow] = f2b(acc[mf][nf][r]);
        }
    __syncthreads();
#pragma unroll
    for (int rr = 0; rr < 6; ++rr){
      int c  = rr*16 + (tid >> 4);
      int mo = (tid & 15) * 8;
      bf16x8 v = *(const bf16x8*)&SM[c * 128 + mo];
      int n = nl0 + c, hh = n >> 6, d = n & 63;
      int m = m0 + mo, b = m >> 11, key = m & 2047;
      *(bf16x8*)&Vtp[(size_t)((b*12 + hh)*64 + d) * 2048 + key] = v;
    }
  }
}

// ---------------- proj GEMM: 64x64 tile, grid 64x12 = 768 blocks (3.0/CU) ----------------
__global__ __launch_bounds__(256) void k_gemm64(const u16* __restrict__ A, const u16* __restrict__ Bt,
                                                float* __restrict__ Co){
  __shared__ __align__(16) u16 SM[8192];
  u16* Al = SM; u16* Bl = SM + 4096;
  const int tid = threadIdx.x;
  const int w = tid >> 6, l = tid & 63;
  const int m0 = blockIdx.x * 64, n0 = blockIdx.y * 64;
  const int wm = (w >> 1) * 32, wn = (w & 1) * 32;
  const int lg = l >> 4, lr = l & 15;
  f32x4 acc[2][2] = {};
  const u16* asrc = A  + (size_t)(m0 + w*16 + (l >> 3)) * 768 + (l & 7) * 8;
  const u16* bsrc = Bt + (size_t)(n0 + w*16 + (l >> 3)) * 768 + (l & 7) * 8;
  for (int k0 = 0; k0 < 768; k0 += 64){
#pragma unroll
    for (int i = 0; i < 2; ++i){
      GLD16(asrc + (size_t)(i*8)*768 + k0, &Al[(w*16 + i*8) * 64]);
      GLD16(bsrc + (size_t)(i*8)*768 + k0, &Bl[(w*16 + i*8) * 64]);
    }
    __syncthreads();
    bf16x8 af[2][2], bfr[2][2];
#pragma unroll
    for (int mf = 0; mf < 2; ++mf)
#pragma unroll
      for (int ks = 0; ks < 2; ++ks){
        af[mf][ks]  = *(const bf16x8*)&Al[(wm + mf*16 + lr) * 64 + ks*32 + lg*8];
        bfr[mf][ks] = *(const bf16x8*)&Bl[(wn + mf*16 + lr) * 64 + ks*32 + lg*8];
      }
#pragma unroll
    for (int ks = 0; ks < 2; ++ks)
#pragma unroll
      for (int mf = 0; mf < 2; ++mf)
#pragma unroll
        for (int nf = 0; nf < 2; ++nf)
          acc[mf][nf] = __builtin_amdgcn_mfma_f32_16x16x32_bf16(af[mf][ks], bfr[nf][ks], acc[mf][nf], 0, 0, 0);  // bfr[nf] (r9 fix, keep)
    __syncthreads();
  }
#pragma unroll
  for (int mf = 0; mf < 2; ++mf)
#pragma unroll
    for (int nf = 0; nf < 2; ++nf)
#pragma unroll
      for (int r = 0; r < 4; ++r)
        Co[(size_t)(m0 + wm + mf*16 + lg*4 + r) * 768 + n0 + wn + nf*16 + lr] = acc[mf][nf][r];
}

// ---------------- flash attention: 8-wave, K-staged-only, V direct from L2, XCD-swizzled ----------------
// r20: LAUNCH-BOUNDS FIX. r17-r19 used __launch_bounds__(512, 6), which produced a 40-VGPR cap
// (compiler budgeted ~12 waves/SIMD) — below the ~56-VGPR live set -> 16 spilled VGPRs/thread/tile
// -> 250+ MB scratch writes (WRITE_SIZE counter) and 176 µs. r17's staged-V variant only escaped
// because its live set ~= 40 (its WRITE_SIZE 12.6 MB vs 6.3 ideal shows it was already spilling
// mildly). Fix: __launch_bounds__(512, 3) — cap >= 85 VGPRs under either interpretation of arg 2;
// grid 768 still gives 3 blocks/CU. Everything else identical to r19 (V direct from L2, K-only
// 3-buffer counted-vmcnt(1) pipeline, bijective XCD swizzle, 24 KB LDS).
__global__ __launch_bounds__(512, 3) void k_attn(const u16* __restrict__ Qp, const u16* __restrict__ Kp,
                                                 const u16* __restrict__ Vtp, u16* __restrict__ AO){
  __shared__ __align__(16) u16 SM[12288];        // 24 KB: K 3x4096 u16; epilogue f32 scratch (16.9KB) reuses
  const int tid = threadIdx.x, w = tid >> 6, l = tid & 63;
  const int QH = w >> 1, KH = w & 1;
  const int lg = l >> 4, lr = l & 15;
  const int p = blockIdx.x;
  const int lgid = ((p & 7) * 96) + (p >> 3);    // bijective XCD swizzle (768 % 8 == 0)
  const int qt_b = lgid & 31, bh = lgid >> 5;
  const int b = bh / 12, hh = bh - b * 12;
  const size_t base = (size_t)bh * (2048 * 64);
  const u16* Qg = Qp + base; const u16* Kg = Kp + base; const u16* Vg = Vtp + base;
  const int q0w = qt_b * 64 + QH * 16;
  const int rsw = (lr & 7) * 8;                  // read-side XOR (K only)

  // Q B-fragments: qf[ks]: q = q0w + lr, d = ks*32 + lg*8 + j
  bf16x8 qf[2];
#pragma unroll
  for (int ks = 0; ks < 2; ++ks)
    qf[ks] = *(const bf16x8*)&Qg[(size_t)(q0w + lr) * 64 + ks*32 + lg*8];

  f32x4 oacc[4] = {};                            // [nf]: O[d=nf*16+lg*4+r][q=lr] (key-half partial)
  float lp = 0.f;

  // K staging: 512 threads x 1 GLD16 cover the 64x64 u16 K tile.
  // dest row p_ = tid>>3, col octet tid&7; T21 source col16 = (tid&7)^(p_&7).
  // K source rows permuted: srckey(p_) = 32*(p_>>5) + 8*((p_>>2)&3) + 4*((p_>>4)&1) + (p_&3).
  const int p_  = tid >> 3;
  const int sk  = 32*(p_ >> 5) + 8*((p_ >> 2) & 3) + 4*((p_ >> 4) & 1) + (p_ & 3);
  const int cs8 = (((tid & 7) ^ (p_ & 7)) << 3);
  const u16* kp = Kg + (size_t)sk * 64 + cs8;    // induction: += 4096 per tile
  const int drow = p_ * 64;
  u16* const K0 = SM + 0    + drow;
  u16* const K1 = SM + 4096 + drow;
  u16* const K2 = SM + 8192 + drow;

  // V direct-from-global pointer: row d = nf*16 + lr (offset nf*32768), col = k0 + KH*32 + lg*8
  const u16* vp = Vg + (size_t)lr * 2048 + KH*32 + lg*8;   // induction: += 64 per tile

  auto compute = [&](const u16* Kc, bf16x8 vf0, bf16x8 vf1, bf16x8 vf2, bf16x8 vf3){
    f32x4 s[2] = {};                             // s[kf]: C col=lr=q, row=kf*16+4lg+r -> key 8lg+4kf+r
    bf16x8 kfr[2][2];
#pragma unroll
    for (int kf = 0; kf < 2; ++kf)
#pragma unroll
      for (int ks = 0; ks < 2; ++ks)
        kfr[kf][ks] = *(const bf16x8*)&Kc[(KH*32 + kf*16 + lr) * 64 + ((ks*32 + lg*8) ^ rsw)];
    __builtin_amdgcn_s_setprio(1);
#pragma unroll
    for (int ks = 0; ks < 2; ++ks)
#pragma unroll
      for (int kf = 0; kf < 2; ++kf)
        s[kf] = __builtin_amdgcn_mfma_f32_16x16x32_bf16(kfr[kf][ks], qf[ks], s[kf], 0, 0, 0);
    __builtin_amdgcn_s_setprio(0);

    // P = exp2(S'); B-frag slot j: j=0..3 from s[0], j=4..7 from s[1] (key = KH*32 + 8lg + j)
    float p00 = __builtin_exp2f(s[0][0]);
    float p01 = __builtin_exp2f(s[0][1]);
    float p02 = __builtin_exp2f(s[0][2]);
    float p03 = __builtin_exp2f(s[0][3]);
    float p10 = __builtin_exp2f(s[1][0]);
    float p11 = __builtin_exp2f(s[1][1]);
    float p12 = __builtin_exp2f(s[1][2]);
    float p13 = __builtin_exp2f(s[1][3]);
    lp += ((p00 + p01) + (p02 + p03)) + ((p10 + p11) + (p12 + p13));
    union { uint32_t u[4]; bf16x8 v; } fr;
    fr.u[0] = pkrhu(p00, p01);
    fr.u[1] = pkrhu(p02, p03);
    fr.u[2] = pkrhu(p10, p11);
    fr.u[3] = pkrhu(p12, p13);

    __builtin_amdgcn_s_setprio(1);
    oacc[0] = __builtin_amdgcn_mfma_f32_16x16x32_bf16(vf0, fr.v, oacc[0], 0, 0, 0);
    oacc[1] = __builtin_amdgcn_mfma_f32_16x16x32_bf16(vf1, fr.v, oacc[1], 0, 0, 0);
    oacc[2] = __builtin_amdgcn_mfma_f32_16x16x32_bf16(vf2, fr.v, oacc[2], 0, 0, 0);
    oacc[3] = __builtin_amdgcn_mfma_f32_16x16x32_bf16(vf3, fr.v, oacc[3], 0, 0, 0);
    __builtin_amdgcn_s_setprio(0);
  };

  // V loads as 4 NAMED registers (by value — never an addressable array)
#define VLOAD4  vf0 = *(const bf16x8*)(vp);            \
                vf1 = *(const bf16x8*)(vp + 32768);    \
                vf2 = *(const bf16x8*)(vp + 65536);    \
                vf3 = *(const bf16x8*)(vp + 98304);    \
                vp += 64
#define STAGE1(KD) do { GLD16(kp, KD); kp += 4096; } while(0)
#define BAR_CNT1  do { asm volatile("s_waitcnt vmcnt(1)" ::: "memory"); \
                       __builtin_amdgcn_s_barrier(); __builtin_amdgcn_sched_barrier(0); } while(0)
#define BAR_CNT0  do { asm volatile("s_waitcnt vmcnt(0)" ::: "memory"); \
                       __builtin_amdgcn_s_barrier(); __builtin_amdgcn_sched_barrier(0); } while(0)

  // prologue: stage K t0->buf0, t1->buf1; ensure t0 landed (t1's load may remain in flight)
  STAGE1(K0);
  STAGE1(K1);
  BAR_CNT1;

  bf16x8 vf0, vf1, vf2, vf3;
  for (int g = 0; g < 10; ++g){
    VLOAD4; STAGE1(K2); compute(SM + 0,    vf0, vf1, vf2, vf3); BAR_CNT1;   // t=3g
    VLOAD4; STAGE1(K0); compute(SM + 4096, vf0, vf1, vf2, vf3); BAR_CNT1;   // t=3g+1
    VLOAD4; STAGE1(K1); compute(SM + 8192, vf0, vf1, vf2, vf3); BAR_CNT1;   // t=3g+2
  }
  VLOAD4; compute(SM + 0,    vf0, vf1, vf2, vf3);   // t=30 (no prefetch)
  BAR_CNT0;                                         // ensure K t=31 landed
  VLOAD4; compute(SM + 4096, vf0, vf1, vf2, vf3);   // t=31

#undef VLOAD4
#undef STAGE1
#undef BAR_CNT1
#undef BAR_CNT0

  // per-q row sum over this wave's key half (q = lr; reduce over lg lanes)
  float lt = lp;
  lt += __shfl_xor(lt, 16);
  lt += __shfl_xor(lt, 32);

  __syncthreads();   // full sync before reusing SM as f32 scratch
  // split-key merge (pure sums under no-max): KH=1 publishes, KH=0 merges + stores.
  float* Osc = (float*)SM;                        // [64 q][65] f32 (stride 65, conflict-free) = 16640 B
  float* Lsc = Osc + 64 * 65;                     // [64 q] f32  (total 16896 B <= 24576 B)
  if (KH == 1){
#pragma unroll
    for (int nf = 0; nf < 4; ++nf)
#pragma unroll
      for (int r = 0; r < 4; ++r)
        Osc[(QH*16 + lr) * 65 + nf*16 + lg*4 + r] = oacc[nf][r];
    if (lg == 0) Lsc[QH*16 + lr] = lt;
  }
  __syncthreads();
  if (KH == 0){
    float inv = 1.0f / (lt + Lsc[QH*16 + lr]);
#pragma unroll
    for (int nf = 0; nf < 4; ++nf)
#pragma unroll
      for (int r = 0; r < 4; ++r){
        float o = oacc[nf][r] + Osc[(QH*16 + lr) * 65 + nf*16 + lg*4 + r];
        AO[(size_t)((b << 11) + q0w + lr) * 768 + hh*64 + nf*16 + lg*4 + r] = f2b(o * inv);
      }
  }
}

extern "C" void kernel_launch(void* const* d_in, const int* in_sizes, int n_in,
                              void* d_out, int out_size, void* d_ws, size_t ws_size,
                              hipStream_t stream){
  const float* x      = (const float*)d_in[0];
  const float* w_qkv  = (const float*)d_in[1];
  const float* w_proj = (const float*)d_in[2];
  float* out = (float*)d_out;
  char* ws = (char*)d_ws;
  u16* Xb     = (u16*)(ws + 0);
  u16* WqkvT  = (u16*)(ws + 6291456);
  u16* WprojT = (u16*)(ws + 9830400);
  u16* Qp     = (u16*)(ws + 11010048);
  u16* Kp     = (u16*)(ws + 17301504);
  u16* Vtp    = (u16*)(ws + 23592960);
  u16* AO     = (u16*)(ws + 29884416);

  k_prep<<<3840, 256, 0, stream>>>(x, Xb, w_qkv, WqkvT, w_proj, WprojT);
  k_gemmqkv<<<dim3(32, 24), 256, 0, stream>>>(Xb, WqkvT, Qp, Kp, Vtp);
  k_attn<<<768, 512, 0, stream>>>(Qp, Kp, Vtp, AO);
  k_gemm64<<<dim3(64, 12), 256, 0, stream>>>(AO, WprojT, out);
}

// Round 21
// 88.268 us; speedup vs baseline: 2.4084x; 1.7351x over previous
//
#include <hip/hip_runtime.h>
#include <hip/hip_bf16.h>
#include <stdint.h>

typedef uint16_t u16;
typedef __attribute__((ext_vector_type(4))) float f32x4;
typedef __attribute__((ext_vector_type(8))) short bf16x8;

#define LOG2E 1.4426950408889634f

static __device__ __forceinline__ u16 f2b(float x){
  union { float f; uint32_t u; } a; a.f = x;
  uint32_t r = a.u + 0x7FFFu + ((a.u >> 16) & 1u);
  return (u16)(r >> 16);
}

// pack two f32 -> two bf16 (round-half-up) in 3 VALU: add, add, v_perm_b32
static __device__ __forceinline__ uint32_t pkrhu(float lo, float hi){
  union { float f; uint32_t u; } a, b; a.f = lo; b.f = hi;
  return __builtin_amdgcn_perm(b.u + 0x8000u, a.u + 0x8000u, 0x07060302u);
}

#define GLD16(g, l) __builtin_amdgcn_global_load_lds((const __attribute__((address_space(1))) void*)(g), (__attribute__((address_space(3))) void*)(l), 16, 0, 0)

// ---------------- fused prep: cast x (1536 blk) | tcast w_qkv (1728 blk) | tcast w_proj (576 blk) ----------------
__global__ __launch_bounds__(256) void k_prep(const float* __restrict__ x, u16* __restrict__ Xb,
                                              const float* __restrict__ wqkv, u16* __restrict__ WqkvT,
                                              const float* __restrict__ wproj, u16* __restrict__ WprojT){
  __shared__ float t[32][33];
  const int bid = blockIdx.x, tid = threadIdx.x;
  if (bid < 1536){
    int i = bid * 256 + tid;
    const f32x4* p = (const f32x4*)(x + (size_t)i * 8);
    f32x4 a = p[0], b = p[1];
    u16 h[8];
#pragma unroll
    for (int j = 0; j < 4; ++j){ h[j] = f2b(a[j]); h[4+j] = f2b(b[j]); }
    *(bf16x8*)(Xb + (size_t)i * 8) = *(const bf16x8*)h;
    return;
  }
  const float* in; u16* out; int R, C, bx, by;
  if (bid < 1536 + 1728){
    int q = bid - 1536; in = wqkv; out = WqkvT; R = 768; C = 2304; bx = q % 72; by = q / 72;
  } else {
    int q = bid - 1536 - 1728; in = wproj; out = WprojT; R = 768; C = 768; bx = q % 24; by = q / 24;
  }
  int c0 = bx * 32, r0 = by * 32;
  int tx = tid & 31, ty = tid >> 5;
#pragma unroll
  for (int i = 0; i < 32; i += 8) t[ty + i][tx] = in[(size_t)(r0 + ty + i) * C + c0 + tx];
  __syncthreads();
#pragma unroll
  for (int i = 0; i < 32; i += 8) out[(size_t)(c0 + ty + i) * R + r0 + tx] = f2b(t[tx][ty + i]);
}

// ---------------- QKV GEMM: 128x96 tile, grid 32x24 = 768 blocks (3.0/CU) ----------------
__global__ __launch_bounds__(256) void k_gemmqkv(const u16* __restrict__ A, const u16* __restrict__ Bt,
                                                 u16* __restrict__ Qp, u16* __restrict__ Kp, u16* __restrict__ Vtp){
  __shared__ __align__(16) u16 SM[14336];
  u16* Al = SM; u16* Bl = SM + 8192;
  const int tid = threadIdx.x;
  const int w = tid >> 6, l = tid & 63;
  const int m0 = blockIdx.x * 128, n0 = blockIdx.y * 96;
  const int wm = (w >> 1) * 64, wn = (w & 1) * 48;
  const int lg = l >> 4, lr = l & 15;
  f32x4 acc[4][3] = {};
  const u16* asrc = A  + (size_t)(m0 + w*32 + (l >> 3)) * 768 + (l & 7) * 8;
  const u16* bsrc = Bt + (size_t)(n0 + w*24 + (l >> 3)) * 768 + (l & 7) * 8;
  for (int k0 = 0; k0 < 768; k0 += 64){
#pragma unroll
    for (int i = 0; i < 4; ++i)
      GLD16(asrc + (size_t)(i*8)*768 + k0, &Al[(w*32 + i*8) * 64]);
#pragma unroll
    for (int i = 0; i < 3; ++i)
      GLD16(bsrc + (size_t)(i*8)*768 + k0, &Bl[(w*24 + i*8) * 64]);
    __syncthreads();
    bf16x8 af[4][2], bfr[3][2];
#pragma unroll
    for (int mf = 0; mf < 4; ++mf)
#pragma unroll
      for (int ks = 0; ks < 2; ++ks)
        af[mf][ks] = *(const bf16x8*)&Al[(wm + mf*16 + lr) * 64 + ks*32 + lg*8];
#pragma unroll
    for (int nf = 0; nf < 3; ++nf)
#pragma unroll
      for (int ks = 0; ks < 2; ++ks)
        bfr[nf][ks] = *(const bf16x8*)&Bl[(wn + nf*16 + lr) * 64 + ks*32 + lg*8];
#pragma unroll
    for (int ks = 0; ks < 2; ++ks)
#pragma unroll
      for (int mf = 0; mf < 4; ++mf)
#pragma unroll
        for (int nf = 0; nf < 3; ++nf)
          acc[mf][nf] = __builtin_amdgcn_mfma_f32_16x16x32_bf16(af[mf][ks], bfr[nf][ks], acc[mf][nf], 0, 0, 0);
    __syncthreads();
  }

  const int which = n0 / 768;
  const int nl0 = n0 - which * 768;
  if (which < 2){
    u16* dst = (which == 0) ? Qp : Kp;
    const float sc = (which == 0) ? 0.125f * LOG2E : 1.0f;
#pragma unroll
    for (int mf = 0; mf < 4; ++mf)
#pragma unroll
      for (int nf = 0; nf < 3; ++nf)
#pragma unroll
        for (int r = 0; r < 4; ++r){
          int m = m0 + wm + mf*16 + lg*4 + r;
          int n = nl0 + wn + nf*16 + lr;
          int b = m >> 11, row = m & 2047, hh = n >> 6, d = n & 63;
          dst[(size_t)((b*12 + hh)*2048 + row) * 64 + d] = f2b(acc[mf][nf][r] * sc);
        }
  } else {
#pragma unroll
    for (int mf = 0; mf < 4; ++mf)
#pragma unroll
      for (int nf = 0; nf < 3; ++nf)
#pragma unroll
        for (int r = 0; r < 4; ++r){
          int mrow = wm + mf*16 + lg*4 + r;
          int c    = wn + nf*16 + lr;
          SM[c * 128 + mrow] = f2b(acc[mf][nf][r]);
        }
    __syncthreads();
#pragma unroll
    for (int rr = 0; rr < 6; ++rr){
      int c  = rr*16 + (tid >> 4);
      int mo = (tid & 15) * 8;
      bf16x8 v = *(const bf16x8*)&SM[c * 128 + mo];
      int n = nl0 + c, hh = n >> 6, d = n & 63;
      int m = m0 + mo, b = m >> 11, key = m & 2047;
      *(bf16x8*)&Vtp[(size_t)((b*12 + hh)*64 + d) * 2048 + key] = v;
    }
  }
}

// ---------------- proj GEMM: 64x64 tile, grid 64x12 = 768 blocks (3.0/CU) ----------------
__global__ __launch_bounds__(256) void k_gemm64(const u16* __restrict__ A, const u16* __restrict__ Bt,
                                                float* __restrict__ Co){
  __shared__ __align__(16) u16 SM[8192];
  u16* Al = SM; u16* Bl = SM + 4096;
  const int tid = threadIdx.x;
  const int w = tid >> 6, l = tid & 63;
  const int m0 = blockIdx.x * 64, n0 = blockIdx.y * 64;
  const int wm = (w >> 1) * 32, wn = (w & 1) * 32;
  const int lg = l >> 4, lr = l & 15;
  f32x4 acc[2][2] = {};
  const u16* asrc = A  + (size_t)(m0 + w*16 + (l >> 3)) * 768 + (l & 7) * 8;
  const u16* bsrc = Bt + (size_t)(n0 + w*16 + (l >> 3)) * 768 + (l & 7) * 8;
  for (int k0 = 0; k0 < 768; k0 += 64){
#pragma unroll
    for (int i = 0; i < 2; ++i){
      GLD16(asrc + (size_t)(i*8)*768 + k0, &Al[(w*16 + i*8) * 64]);
      GLD16(bsrc + (size_t)(i*8)*768 + k0, &Bl[(w*16 + i*8) * 64]);
    }
    __syncthreads();
    bf16x8 af[2][2], bfr[2][2];
#pragma unroll
    for (int mf = 0; mf < 2; ++mf)
#pragma unroll
      for (int ks = 0; ks < 2; ++ks){
        af[mf][ks]  = *(const bf16x8*)&Al[(wm + mf*16 + lr) * 64 + ks*32 + lg*8];
        bfr[mf][ks] = *(const bf16x8*)&Bl[(wn + mf*16 + lr) * 64 + ks*32 + lg*8];
      }
#pragma unroll
    for (int ks = 0; ks < 2; ++ks)
#pragma unroll
      for (int mf = 0; mf < 2; ++mf)
#pragma unroll
        for (int nf = 0; nf < 2; ++nf)
          acc[mf][nf] = __builtin_amdgcn_mfma_f32_16x16x32_bf16(af[mf][ks], bfr[nf][ks], acc[mf][nf], 0, 0, 0);  // bfr[nf] (r9 fix, keep)
    __syncthreads();
  }
#pragma unroll
  for (int mf = 0; mf < 2; ++mf)
#pragma unroll
    for (int nf = 0; nf < 2; ++nf)
#pragma unroll
      for (int r = 0; r < 4; ++r)
        Co[(size_t)(m0 + wm + mf*16 + lg*4 + r) * 768 + n0 + wn + nf*16 + lr] = acc[mf][nf][r];
}

// ---------------- flash attention: 8-wave, K+V GLD16-staged, 3-buffer counted-vmcnt(2) ----------------
// r21: REVERT to r17's proven staged-V structure (50.8 µs) with the launch-bounds fix it never got.
// r17 ran under a 40-VGPR cap from __launch_bounds__(512,6) and was mildly spilling (WRITE_SIZE
// 12.3 MB vs 6.3 ideal). V-direct (r18-r20) is falsified: the per-lane V fragment gather
// (64 lanes x 16B at 4KB stride) is uncoalesced -> 114 µs even with zero spill. Staged V keeps
// every global access coalesced (GLD16) and every fragment read in LDS.
__global__ __launch_bounds__(512, 3) void k_attn(const u16* __restrict__ Qp, const u16* __restrict__ Kp,
                                                 const u16* __restrict__ Vtp, u16* __restrict__ AO){
  __shared__ __align__(16) u16 SM[24576];        // 48 KB: K 3x4096 | V 3x4096; epilogue f32 scratch reuses
  const int tid = threadIdx.x, w = tid >> 6, l = tid & 63;
  const int QH = w >> 1, KH = w & 1;
  const int lg = l >> 4, lr = l & 15;
  const int qt_b = blockIdx.x, bh = blockIdx.y;
  const int b = bh / 12, hh = bh - b * 12;
  const size_t base = (size_t)bh * (2048 * 64);
  const u16* Qg = Qp + base; const u16* Kg = Kp + base; const u16* Vg = Vtp + base;
  const int q0w = qt_b * 64 + QH * 16;
  const int rsw = (lr & 7) * 8;                  // read-side XOR

  // Q B-fragments: qf[ks]: q = q0w + lr, d = ks*32 + lg*8 + j
  bf16x8 qf[2];
#pragma unroll
  for (int ks = 0; ks < 2; ++ks)
    qf[ks] = *(const bf16x8*)&Qg[(size_t)(q0w + lr) * 64 + ks*32 + lg*8];

  f32x4 oacc[4] = {};                            // [nf]: O[d=nf*16+lg*4+r][q=lr] (key-half partial)
  float lp = 0.f;

  // staging: 512 threads x 1 GLD16 each cover the 64x64 u16 K tile and V tile.
  // dest row p_ = tid>>3 (0..63), col octet tid&7; T21 source col16 = (tid&7)^(p_&7).
  // K source rows permuted: srckey(p_) = 32*(p_>>5) + 8*((p_>>2)&3) + 4*((p_>>4)&1) + (p_&3).
  const int p_  = tid >> 3;
  const int sk  = 32*(p_ >> 5) + 8*((p_ >> 2) & 3) + 4*((p_ >> 4) & 1) + (p_ & 3);
  const int cs8 = (((tid & 7) ^ (p_ & 7)) << 3);
  const u16* kp = Kg + (size_t)sk * 64 + cs8;    // induction: += 4096 per tile
  const u16* vp = Vg + ((size_t)p_ << 11) + cs8; // induction: += 64 per tile
  const int drow = p_ * 64;                      // LDS dest offset (u16)
  u16* const K0 = SM + 0     + drow;  u16* const V0 = SM + 12288 + drow;
  u16* const K1 = SM + 4096  + drow;  u16* const V1 = SM + 16384 + drow;
  u16* const K2 = SM + 8192  + drow;  u16* const V2 = SM + 20480 + drow;

  auto compute = [&](const u16* Kc, const u16* Vc){
    f32x4 s[2] = {};                             // s[kf]: C col=lr=q, row=kf*16+4lg+r -> key 8lg+4kf+r
    bf16x8 kfr[2][2];
#pragma unroll
    for (int kf = 0; kf < 2; ++kf)
#pragma unroll
      for (int ks = 0; ks < 2; ++ks)
        kfr[kf][ks] = *(const bf16x8*)&Kc[(KH*32 + kf*16 + lr) * 64 + ((ks*32 + lg*8) ^ rsw)];
    __builtin_amdgcn_s_setprio(1);
#pragma unroll
    for (int ks = 0; ks < 2; ++ks)
#pragma unroll
      for (int kf = 0; kf < 2; ++kf)
        s[kf] = __builtin_amdgcn_mfma_f32_16x16x32_bf16(kfr[kf][ks], qf[ks], s[kf], 0, 0, 0);
    __builtin_amdgcn_s_setprio(0);

    // P = exp2(S'); B-frag slot j: j=0..3 from s[0], j=4..7 from s[1] (key = KH*32 + 8lg + j)
    float p00 = __builtin_exp2f(s[0][0]);
    float p01 = __builtin_exp2f(s[0][1]);
    float p02 = __builtin_exp2f(s[0][2]);
    float p03 = __builtin_exp2f(s[0][3]);
    float p10 = __builtin_exp2f(s[1][0]);
    float p11 = __builtin_exp2f(s[1][1]);
    float p12 = __builtin_exp2f(s[1][2]);
    float p13 = __builtin_exp2f(s[1][3]);
    lp += ((p00 + p01) + (p02 + p03)) + ((p10 + p11) + (p12 + p13));
    union { uint32_t u[4]; bf16x8 v; } fr;
    fr.u[0] = pkrhu(p00, p01);
    fr.u[1] = pkrhu(p02, p03);
    fr.u[2] = pkrhu(p10, p11);
    fr.u[3] = pkrhu(p12, p13);

    bf16x8 vfr[4];
#pragma unroll
    for (int nf = 0; nf < 4; ++nf)
      vfr[nf] = *(const bf16x8*)&Vc[(nf*16 + lr) * 64 + ((KH*32 + lg*8) ^ rsw)];
    __builtin_amdgcn_s_setprio(1);
#pragma unroll
    for (int nf = 0; nf < 4; ++nf)
      oacc[nf] = __builtin_amdgcn_mfma_f32_16x16x32_bf16(vfr[nf], fr.v, oacc[nf], 0, 0, 0);
    __builtin_amdgcn_s_setprio(0);
  };

#define STAGE2(KD, VD) do { GLD16(kp, KD); GLD16(vp, VD); kp += 4096; vp += 64; } while(0)
#define BAR_CNT2  do { asm volatile("s_waitcnt vmcnt(2)" ::: "memory"); \
                       __builtin_amdgcn_s_barrier(); __builtin_amdgcn_sched_barrier(0); } while(0)
#define BAR_CNT0  do { asm volatile("s_waitcnt vmcnt(0)" ::: "memory"); \
                       __builtin_amdgcn_s_barrier(); __builtin_amdgcn_sched_barrier(0); } while(0)

  // prologue: stage t0->buf0, t1->buf1; ensure t0 landed (t1's 2 loads may remain in flight)
  STAGE2(K0, V0);
  STAGE2(K1, V1);
  BAR_CNT2;

  for (int g = 0; g < 10; ++g){
    STAGE2(K2, V2);  compute(SM + 0,    SM + 12288);  BAR_CNT2;   // t=3g
    STAGE2(K0, V0);  compute(SM + 4096, SM + 16384);  BAR_CNT2;   // t=3g+1
    STAGE2(K1, V1);  compute(SM + 8192, SM + 20480);  BAR_CNT2;   // t=3g+2
  }
  compute(SM + 0,    SM + 12288);   // t=30
  BAR_CNT0;                         // ensure t=31 landed
  compute(SM + 4096, SM + 16384);   // t=31

#undef STAGE2
#undef BAR_CNT2
#undef BAR_CNT0

  // per-q row sum over this wave's key half (q = lr; reduce over lg lanes)
  float lt = lp;
  lt += __shfl_xor(lt, 16);
  lt += __shfl_xor(lt, 32);

  __syncthreads();   // full sync before reusing SM as f32 scratch
  // split-key merge (pure sums under no-max): KH=1 publishes, KH=0 merges + stores.
  float* Osc = (float*)SM;                        // [64 q][65] f32 (stride 65, conflict-free)
  float* Lsc = Osc + 64 * 65;                     // [64 q] f32  (total 16896 B <= 49152 B)
  if (KH == 1){
#pragma unroll
    for (int nf = 0; nf < 4; ++nf)
#pragma unroll
      for (int r = 0; r < 4; ++r)
        Osc[(QH*16 + lr) * 65 + nf*16 + lg*4 + r] = oacc[nf][r];
    if (lg == 0) Lsc[QH*16 + lr] = lt;
  }
  __syncthreads();
  if (KH == 0){
    float inv = 1.0f / (lt + Lsc[QH*16 + lr]);
#pragma unroll
    for (int nf = 0; nf < 4; ++nf)
#pragma unroll
      for (int r = 0; r < 4; ++r){
        float o = oacc[nf][r] + Osc[(QH*16 + lr) * 65 + nf*16 + lg*4 + r];
        AO[(size_t)((b << 11) + q0w + lr) * 768 + hh*64 + nf*16 + lg*4 + r] = f2b(o * inv);
      }
  }
}

extern "C" void kernel_launch(void* const* d_in, const int* in_sizes, int n_in,
                              void* d_out, int out_size, void* d_ws, size_t ws_size,
                              hipStream_t stream){
  const float* x      = (const float*)d_in[0];
  const float* w_qkv  = (const float*)d_in[1];
  const float* w_proj = (const float*)d_in[2];
  float* out = (float*)d_out;
  char* ws = (char*)d_ws;
  u16* Xb     = (u16*)(ws + 0);
  u16* WqkvT  = (u16*)(ws + 6291456);
  u16* WprojT = (u16*)(ws + 9830400);
  u16* Qp     = (u16*)(ws + 11010048);
  u16* Kp     = (u16*)(ws + 17301504);
  u16* Vtp    = (u16*)(ws + 23592960);
  u16* AO     = (u16*)(ws + 29884416);

  k_prep<<<3840, 256, 0, stream>>>(x, Xb, w_qkv, WqkvT, w_proj, WprojT);
  k_gemmqkv<<<dim3(32, 24), 256, 0, stream>>>(Xb, WqkvT, Qp, Kp, Vtp);
  k_attn<<<dim3(32, 24), 512, 0, stream>>>(Qp, Kp, Vtp, AO);
  k_gemm64<<<dim3(64, 12), 256, 0, stream>>>(AO, WprojT, out);
}

// Round 22
// 87.340 us; speedup vs baseline: 2.4340x; 1.0106x over previous
//
#include <hip/hip_runtime.h>
#include <hip/hip_bf16.h>
#include <stdint.h>

typedef uint16_t u16;
typedef __attribute__((ext_vector_type(4))) float f32x4;
typedef __attribute__((ext_vector_type(8))) short bf16x8;

#define LOG2E 1.4426950408889634f

static __device__ __forceinline__ u16 f2b(float x){
  union { float f; uint32_t u; } a; a.f = x;
  uint32_t r = a.u + 0x7FFFu + ((a.u >> 16) & 1u);
  return (u16)(r >> 16);
}

// pack two f32 -> two bf16 (round-half-up) in 3 VALU: add, add, v_perm_b32
static __device__ __forceinline__ uint32_t pkrhu(float lo, float hi){
  union { float f; uint32_t u; } a, b; a.f = lo; b.f = hi;
  return __builtin_amdgcn_perm(b.u + 0x8000u, a.u + 0x8000u, 0x07060302u);
}

#define GLD16(g, l) __builtin_amdgcn_global_load_lds((const __attribute__((address_space(1))) void*)(g), (__attribute__((address_space(3))) void*)(l), 16, 0, 0)

// ---------------- fused prep: cast x (1536 blk) | tcast w_qkv (1728 blk) | tcast w_proj (576 blk) ----------------
__global__ __launch_bounds__(256) void k_prep(const float* __restrict__ x, u16* __restrict__ Xb,
                                              const float* __restrict__ wqkv, u16* __restrict__ WqkvT,
                                              const float* __restrict__ wproj, u16* __restrict__ WprojT){
  __shared__ float t[32][33];
  const int bid = blockIdx.x, tid = threadIdx.x;
  if (bid < 1536){
    int i = bid * 256 + tid;
    const f32x4* p = (const f32x4*)(x + (size_t)i * 8);
    f32x4 a = p[0], b = p[1];
    u16 h[8];
#pragma unroll
    for (int j = 0; j < 4; ++j){ h[j] = f2b(a[j]); h[4+j] = f2b(b[j]); }
    *(bf16x8*)(Xb + (size_t)i * 8) = *(const bf16x8*)h;
    return;
  }
  const float* in; u16* out; int R, C, bx, by;
  if (bid < 1536 + 1728){
    int q = bid - 1536; in = wqkv; out = WqkvT; R = 768; C = 2304; bx = q % 72; by = q / 72;
  } else {
    int q = bid - 1536 - 1728; in = wproj; out = WprojT; R = 768; C = 768; bx = q % 24; by = q / 24;
  }
  int c0 = bx * 32, r0 = by * 32;
  int tx = tid & 31, ty = tid >> 5;
#pragma unroll
  for (int i = 0; i < 32; i += 8) t[ty + i][tx] = in[(size_t)(r0 + ty + i) * C + c0 + tx];
  __syncthreads();
#pragma unroll
  for (int i = 0; i < 32; i += 8) out[(size_t)(c0 + ty + i) * R + r0 + tx] = f2b(t[tx][ty + i]);
}

// ---------------- QKV GEMM: 128x96 tile, BK=32 double-buffered, T21-swizzled ----------------
// r22: (1) old Al[128][64] fragment reads were a 16-way bank conflict (row stride 128B, G4 pattern);
// BK=32 rows (64B) + XOR-octet swizzle (phys oct = logical ^ (row&3), both sides) -> 4-way (~free).
// (2) old loop issued GLD16s then immediately drained them at __syncthreads (full latency exposed);
// now double-buffered: stage tile t+1 -> other buffer BEFORE computing tile t, one barrier/step.
// Dest elem = 8*tid (lane-linear, GLD16-legal). LDS layout: Al0@0 Al1@4096 Bl0@8192 Bl1@11264 (u16).
__global__ __launch_bounds__(256) void k_gemmqkv(const u16* __restrict__ A, const u16* __restrict__ Bt,
                                                 u16* __restrict__ Qp, u16* __restrict__ Kp, u16* __restrict__ Vtp){
  __shared__ __align__(16) u16 SM[14336];   // 28 KB; epilogue V-transpose reuse (96x128=12288) fits
  const int tid = threadIdx.x;
  const int w = tid >> 6, l = tid & 63;
  const int m0 = blockIdx.x * 128, n0 = blockIdx.y * 96;
  const int wm = (w >> 1) * 64, wn = (w & 1) * 48;
  const int lg = l >> 4, lr = l & 15;
  f32x4 acc[4][3] = {};

  // staging: thread t -> dest elem 8t (row t>>2, col octet t&3); source logical octet = (t&3)^((t>>2)&3)
  const int tr = tid >> 2;
  const int soct = ((tid & 3) ^ (tr & 3)) * 8;
  const u16* a0 = A  + (size_t)(m0 + tr) * 768 + soct;        // A rows 0-63   (+= 32 per tile)
  const u16* a1 = A  + (size_t)(m0 + 64 + tr) * 768 + soct;   // A rows 64-127
  const u16* b0 = Bt + (size_t)(n0 + tr) * 768 + soct;        // B rows 0-63
  const u16* b1 = Bt + (size_t)(n0 + 64 + tr) * 768 + soct;   // B rows 64-95 (tid<128 only)
  u16* const A0d = SM + 0     + tid*8;  u16* const A0e = SM + 2048  + tid*8;
  u16* const A1d = SM + 4096  + tid*8;  u16* const A1e = SM + 6144  + tid*8;
  u16* const B0d = SM + 8192  + tid*8;  u16* const B0e = SM + 10240 + tid*8;
  u16* const B1d = SM + 11264 + tid*8;  u16* const B1e = SM + 13312 + tid*8;

#define QSTAGE0 do { GLD16(a0, A0d); GLD16(a1, A0e); GLD16(b0, B0d); if (tid < 128) GLD16(b1, B0e); \
                     a0 += 32; a1 += 32; b0 += 32; b1 += 32; } while(0)
#define QSTAGE1 do { GLD16(a0, A1d); GLD16(a1, A1e); GLD16(b0, B1d); if (tid < 128) GLD16(b1, B1e); \
                     a0 += 32; a1 += 32; b0 += 32; b1 += 32; } while(0)

  const int foct = (lg ^ (lr & 3)) * 8;   // fragment read: phys octet of logical octet lg (row&3 == lr&3)

#define QCOMP(ABASE, BBASE) do {                                                            \
    bf16x8 af[4], bfr[3];                                                                   \
    _Pragma("unroll")                                                                       \
    for (int mf = 0; mf < 4; ++mf)                                                          \
      af[mf] = *(const bf16x8*)&SM[(ABASE) + (wm + mf*16 + lr) * 32 + foct];                \
    _Pragma("unroll")                                                                       \
    for (int nf = 0; nf < 3; ++nf)                                                          \
      bfr[nf] = *(const bf16x8*)&SM[(BBASE) + (wn + nf*16 + lr) * 32 + foct];               \
    _Pragma("unroll")                                                                       \
    for (int mf = 0; mf < 4; ++mf)                                                          \
      _Pragma("unroll")                                                                     \
      for (int nf = 0; nf < 3; ++nf)                                                        \
        acc[mf][nf] = __builtin_amdgcn_mfma_f32_16x16x32_bf16(af[mf], bfr[nf], acc[mf][nf], 0, 0, 0); \
  } while(0)

  // prologue: tile 0 -> buf0
  QSTAGE0;
  __syncthreads();
  for (int i = 0; i < 12; ++i){
    QSTAGE1;                 // tile 2i+1 -> buf1 (latency hides under compute)
    QCOMP(0, 8192);          // compute tile 2i from buf0
    __syncthreads();
    if (i < 11) QSTAGE0;     // tile 2i+2 -> buf0
    QCOMP(4096, 11264);      // compute tile 2i+1 from buf1
    __syncthreads();
  }
#undef QSTAGE0
#undef QSTAGE1
#undef QCOMP

  const int which = n0 / 768;
  const int nl0 = n0 - which * 768;
  if (which < 2){
    u16* dst = (which == 0) ? Qp : Kp;
    const float sc = (which == 0) ? 0.125f * LOG2E : 1.0f;
#pragma unroll
    for (int mf = 0; mf < 4; ++mf)
#pragma unroll
      for (int nf = 0; nf < 3; ++nf)
#pragma unroll
        for (int r = 0; r < 4; ++r){
          int m = m0 + wm + mf*16 + lg*4 + r;
          int n = nl0 + wn + nf*16 + lr;
          int b = m >> 11, row = m & 2047, hh = n >> 6, d = n & 63;
          dst[(size_t)((b*12 + hh)*2048 + row) * 64 + d] = f2b(acc[mf][nf][r] * sc);
        }
  } else {
#pragma unroll
    for (int mf = 0; mf < 4; ++mf)
#pragma unroll
      for (int nf = 0; nf < 3; ++nf)
#pragma unroll
        for (int r = 0; r < 4; ++r){
          int mrow = wm + mf*16 + lg*4 + r;
          int c    = wn + nf*16 + lr;
          SM[c * 128 + mrow] = f2b(acc[mf][nf][r]);
        }
    __syncthreads();
#pragma unroll
    for (int rr = 0; rr < 6; ++rr){
      int c  = rr*16 + (tid >> 4);
      int mo = (tid & 15) * 8;
      bf16x8 v = *(const bf16x8*)&SM[c * 128 + mo];
      int n = nl0 + c, hh = n >> 6, d = n & 63;
      int m = m0 + mo, b = m >> 11, key = m & 2047;
      *(bf16x8*)&Vtp[(size_t)((b*12 + hh)*64 + d) * 2048 + key] = v;
    }
  }
}

// ---------------- proj GEMM: 64x64 tile, grid 64x12 = 768 blocks (3.0/CU) ----------------
__global__ __launch_bounds__(256) void k_gemm64(const u16* __restrict__ A, const u16* __restrict__ Bt,
                                                float* __restrict__ Co){
  __shared__ __align__(16) u16 SM[8192];
  u16* Al = SM; u16* Bl = SM + 4096;
  const int tid = threadIdx.x;
  const int w = tid >> 6, l = tid & 63;
  const int m0 = blockIdx.x * 64, n0 = blockIdx.y * 64;
  const int wm = (w >> 1) * 32, wn = (w & 1) * 32;
  const int lg = l >> 4, lr = l & 15;
  f32x4 acc[2][2] = {};
  const u16* asrc = A  + (size_t)(m0 + w*16 + (l >> 3)) * 768 + (l & 7) * 8;
  const u16* bsrc = Bt + (size_t)(n0 + w*16 + (l >> 3)) * 768 + (l & 7) * 8;
  for (int k0 = 0; k0 < 768; k0 += 64){
#pragma unroll
    for (int i = 0; i < 2; ++i){
      GLD16(asrc + (size_t)(i*8)*768 + k0, &Al[(w*16 + i*8) * 64]);
      GLD16(bsrc + (size_t)(i*8)*768 + k0, &Bl[(w*16 + i*8) * 64]);
    }
    __syncthreads();
    bf16x8 af[2][2], bfr[2][2];
#pragma unroll
    for (int mf = 0; mf < 2; ++mf)
#pragma unroll
      for (int ks = 0; ks < 2; ++ks){
        af[mf][ks]  = *(const bf16x8*)&Al[(wm + mf*16 + lr) * 64 + ks*32 + lg*8];
        bfr[mf][ks] = *(const bf16x8*)&Bl[(wn + mf*16 + lr) * 64 + ks*32 + lg*8];
      }
#pragma unroll
    for (int ks = 0; ks < 2; ++ks)
#pragma unroll
      for (int mf = 0; mf < 2; ++mf)
#pragma unroll
        for (int nf = 0; nf < 2; ++nf)
          acc[mf][nf] = __builtin_amdgcn_mfma_f32_16x16x32_bf16(af[mf][ks], bfr[nf][ks], acc[mf][nf], 0, 0, 0);  // bfr[nf] (r9 fix, keep)
    __syncthreads();
  }
#pragma unroll
  for (int mf = 0; mf < 2; ++mf)
#pragma unroll
    for (int nf = 0; nf < 2; ++nf)
#pragma unroll
      for (int r = 0; r < 4; ++r)
        Co[(size_t)(m0 + wm + mf*16 + lg*4 + r) * 768 + n0 + wn + nf*16 + lr] = acc[mf][nf][r];
}

// ---------------- flash attention: 8-wave, K+V GLD16-staged, 3-buffer counted-vmcnt(2) ----------------
// (r21-verified, 51.3 µs — FROZEN)
__global__ __launch_bounds__(512, 3) void k_attn(const u16* __restrict__ Qp, const u16* __restrict__ Kp,
                                                 const u16* __restrict__ Vtp, u16* __restrict__ AO){
  __shared__ __align__(16) u16 SM[24576];        // 48 KB: K 3x4096 | V 3x4096; epilogue f32 scratch reuses
  const int tid = threadIdx.x, w = tid >> 6, l = tid & 63;
  const int QH = w >> 1, KH = w & 1;
  const int lg = l >> 4, lr = l & 15;
  const int qt_b = blockIdx.x, bh = blockIdx.y;
  const int b = bh / 12, hh = bh - b * 12;
  const size_t base = (size_t)bh * (2048 * 64);
  const u16* Qg = Qp + base; const u16* Kg = Kp + base; const u16* Vg = Vtp + base;
  const int q0w = qt_b * 64 + QH * 16;
  const int rsw = (lr & 7) * 8;                  // read-side XOR

  // Q B-fragments: qf[ks]: q = q0w + lr, d = ks*32 + lg*8 + j
  bf16x8 qf[2];
#pragma unroll
  for (int ks = 0; ks < 2; ++ks)
    qf[ks] = *(const bf16x8*)&Qg[(size_t)(q0w + lr) * 64 + ks*32 + lg*8];

  f32x4 oacc[4] = {};                            // [nf]: O[d=nf*16+lg*4+r][q=lr] (key-half partial)
  float lp = 0.f;

  // staging: 512 threads x 1 GLD16 each cover the 64x64 u16 K tile and V tile.
  // dest row p_ = tid>>3 (0..63), col octet tid&7; T21 source col16 = (tid&7)^(p_&7).
  // K source rows permuted: srckey(p_) = 32*(p_>>5) + 8*((p_>>2)&3) + 4*((p_>>4)&1) + (p_&3).
  const int p_  = tid >> 3;
  const int sk  = 32*(p_ >> 5) + 8*((p_ >> 2) & 3) + 4*((p_ >> 4) & 1) + (p_ & 3);
  const int cs8 = (((tid & 7) ^ (p_ & 7)) << 3);
  const u16* kp = Kg + (size_t)sk * 64 + cs8;    // induction: += 4096 per tile
  const u16* vp = Vg + ((size_t)p_ << 11) + cs8; // induction: += 64 per tile
  const int drow = p_ * 64;                      // LDS dest offset (u16)
  u16* const K0 = SM + 0     + drow;  u16* const V0 = SM + 12288 + drow;
  u16* const K1 = SM + 4096  + drow;  u16* const V1 = SM + 16384 + drow;
  u16* const K2 = SM + 8192  + drow;  u16* const V2 = SM + 20480 + drow;

  auto compute = [&](const u16* Kc, const u16* Vc){
    f32x4 s[2] = {};                             // s[kf]: C col=lr=q, row=kf*16+4lg+r -> key 8lg+4kf+r
    bf16x8 kfr[2][2];
#pragma unroll
    for (int kf = 0; kf < 2; ++kf)
#pragma unroll
      for (int ks = 0; ks < 2; ++ks)
        kfr[kf][ks] = *(const bf16x8*)&Kc[(KH*32 + kf*16 + lr) * 64 + ((ks*32 + lg*8) ^ rsw)];
    __builtin_amdgcn_s_setprio(1);
#pragma unroll
    for (int ks = 0; ks < 2; ++ks)
#pragma unroll
      for (int kf = 0; kf < 2; ++kf)
        s[kf] = __builtin_amdgcn_mfma_f32_16x16x32_bf16(kfr[kf][ks], qf[ks], s[kf], 0, 0, 0);
    __builtin_amdgcn_s_setprio(0);

    // P = exp2(S'); B-frag slot j: j=0..3 from s[0], j=4..7 from s[1] (key = KH*32 + 8lg + j)
    float p00 = __builtin_exp2f(s[0][0]);
    float p01 = __builtin_exp2f(s[0][1]);
    float p02 = __builtin_exp2f(s[0][2]);
    float p03 = __builtin_exp2f(s[0][3]);
    float p10 = __builtin_exp2f(s[1][0]);
    float p11 = __builtin_exp2f(s[1][1]);
    float p12 = __builtin_exp2f(s[1][2]);
    float p13 = __builtin_exp2f(s[1][3]);
    lp += ((p00 + p01) + (p02 + p03)) + ((p10 + p11) + (p12 + p13));
    union { uint32_t u[4]; bf16x8 v; } fr;
    fr.u[0] = pkrhu(p00, p01);
    fr.u[1] = pkrhu(p02, p03);
    fr.u[2] = pkrhu(p10, p11);
    fr.u[3] = pkrhu(p12, p13);

    bf16x8 vfr[4];
#pragma unroll
    for (int nf = 0; nf < 4; ++nf)
      vfr[nf] = *(const bf16x8*)&Vc[(nf*16 + lr) * 64 + ((KH*32 + lg*8) ^ rsw)];
    __builtin_amdgcn_s_setprio(1);
#pragma unroll
    for (int nf = 0; nf < 4; ++nf)
      oacc[nf] = __builtin_amdgcn_mfma_f32_16x16x32_bf16(vfr[nf], fr.v, oacc[nf], 0, 0, 0);
    __builtin_amdgcn_s_setprio(0);
  };

#define STAGE2(KD, VD) do { GLD16(kp, KD); GLD16(vp, VD); kp += 4096; vp += 64; } while(0)
#define BAR_CNT2  do { asm volatile("s_waitcnt vmcnt(2)" ::: "memory"); \
                       __builtin_amdgcn_s_barrier(); __builtin_amdgcn_sched_barrier(0); } while(0)
#define BAR_CNT0  do { asm volatile("s_waitcnt vmcnt(0)" ::: "memory"); \
                       __builtin_amdgcn_s_barrier(); __builtin_amdgcn_sched_barrier(0); } while(0)

  // prologue: stage t0->buf0, t1->buf1; ensure t0 landed (t1's 2 loads may remain in flight)
  STAGE2(K0, V0);
  STAGE2(K1, V1);
  BAR_CNT2;

  for (int g = 0; g < 10; ++g){
    STAGE2(K2, V2);  compute(SM + 0,    SM + 12288);  BAR_CNT2;   // t=3g
    STAGE2(K0, V0);  compute(SM + 4096, SM + 16384);  BAR_CNT2;   // t=3g+1
    STAGE2(K1, V1);  compute(SM + 8192, SM + 20480);  BAR_CNT2;   // t=3g+2
  }
  compute(SM + 0,    SM + 12288);   // t=30
  BAR_CNT0;                         // ensure t=31 landed
  compute(SM + 4096, SM + 16384);   // t=31

#undef STAGE2
#undef BAR_CNT2
#undef BAR_CNT0

  // per-q row sum over this wave's key half (q = lr; reduce over lg lanes)
  float lt = lp;
  lt += __shfl_xor(lt, 16);
  lt += __shfl_xor(lt, 32);

  __syncthreads();   // full sync before reusing SM as f32 scratch
  // split-key merge (pure sums under no-max): KH=1 publishes, KH=0 merges + stores.
  float* Osc = (float*)SM;                        // [64 q][65] f32 (stride 65, conflict-free)
  float* Lsc = Osc + 64 * 65;                     // [64 q] f32  (total 16896 B <= 49152 B)
  if (KH == 1){
#pragma unroll
    for (int nf = 0; nf < 4; ++nf)
#pragma unroll
      for (int r = 0; r < 4; ++r)
        Osc[(QH*16 + lr) * 65 + nf*16 + lg*4 + r] = oacc[nf][r];
    if (lg == 0) Lsc[QH*16 + lr] = lt;
  }
  __syncthreads();
  if (KH == 0){
    float inv = 1.0f / (lt + Lsc[QH*16 + lr]);
#pragma unroll
    for (int nf = 0; nf < 4; ++nf)
#pragma unroll
      for (int r = 0; r < 4; ++r){
        float o = oacc[nf][r] + Osc[(QH*16 + lr) * 65 + nf*16 + lg*4 + r];
        AO[(size_t)((b << 11) + q0w + lr) * 768 + hh*64 + nf*16 + lg*4 + r] = f2b(o * inv);
      }
  }
}

extern "C" void kernel_launch(void* const* d_in, const int* in_sizes, int n_in,
                              void* d_out, int out_size, void* d_ws, size_t ws_size,
                              hipStream_t stream){
  const float* x      = (const float*)d_in[0];
  const float* w_qkv  = (const float*)d_in[1];
  const float* w_proj = (const float*)d_in[2];
  float* out = (float*)d_out;
  char* ws = (char*)d_ws;
  u16* Xb     = (u16*)(ws + 0);
  u16* WqkvT  = (u16*)(ws + 6291456);
  u16* WprojT = (u16*)(ws + 9830400);
  u16* Qp     = (u16*)(ws + 11010048);
  u16* Kp     = (u16*)(ws + 17301504);
  u16* Vtp    = (u16*)(ws + 23592960);
  u16* AO     = (u16*)(ws + 29884416);

  k_prep<<<3840, 256, 0, stream>>>(x, Xb, w_qkv, WqkvT, w_proj, WprojT);
  k_gemmqkv<<<dim3(32, 24), 256, 0, stream>>>(Xb, WqkvT, Qp, Kp, Vtp);
  k_attn<<<dim3(32, 24), 512, 0, stream>>>(Qp, Kp, Vtp, AO);
  k_gemm64<<<dim3(64, 12), 256, 0, stream>>>(AO, WprojT, out);
}

// Round 23
// 85.030 us; speedup vs baseline: 2.5001x; 1.0272x over previous
//
#include <hip/hip_runtime.h>
#include <hip/hip_bf16.h>
#include <stdint.h>

typedef uint16_t u16;
typedef __attribute__((ext_vector_type(4))) float f32x4;
typedef __attribute__((ext_vector_type(8))) short bf16x8;

#define LOG2E 1.4426950408889634f

static __device__ __forceinline__ u16 f2b(float x){
  union { float f; uint32_t u; } a; a.f = x;
  uint32_t r = a.u + 0x7FFFu + ((a.u >> 16) & 1u);
  return (u16)(r >> 16);
}

// pack two f32 -> two bf16 (round-half-up) in 3 VALU: add, add, v_perm_b32
static __device__ __forceinline__ uint32_t pkrhu(float lo, float hi){
  union { float f; uint32_t u; } a, b; a.f = lo; b.f = hi;
  return __builtin_amdgcn_perm(b.u + 0x8000u, a.u + 0x8000u, 0x07060302u);
}

#define GLD16(g, l) __builtin_amdgcn_global_load_lds((const __attribute__((address_space(1))) void*)(g), (__attribute__((address_space(3))) void*)(l), 16, 0, 0)

// ---------------- fused prep: cast x (1536 blk) | tcast w_qkv (1728 blk) | tcast w_proj (576 blk) ----------------
__global__ __launch_bounds__(256) void k_prep(const float* __restrict__ x, u16* __restrict__ Xb,
                                              const float* __restrict__ wqkv, u16* __restrict__ WqkvT,
                                              const float* __restrict__ wproj, u16* __restrict__ WprojT){
  __shared__ float t[32][33];
  const int bid = blockIdx.x, tid = threadIdx.x;
  if (bid < 1536){
    int i = bid * 256 + tid;
    const f32x4* p = (const f32x4*)(x + (size_t)i * 8);
    f32x4 a = p[0], b = p[1];
    u16 h[8];
#pragma unroll
    for (int j = 0; j < 4; ++j){ h[j] = f2b(a[j]); h[4+j] = f2b(b[j]); }
    *(bf16x8*)(Xb + (size_t)i * 8) = *(const bf16x8*)h;
    return;
  }
  const float* in; u16* out; int R, C, bx, by;
  if (bid < 1536 + 1728){
    int q = bid - 1536; in = wqkv; out = WqkvT; R = 768; C = 2304; bx = q % 72; by = q / 72;
  } else {
    int q = bid - 1536 - 1728; in = wproj; out = WprojT; R = 768; C = 768; bx = q % 24; by = q / 24;
  }
  int c0 = bx * 32, r0 = by * 32;
  int tx = tid & 31, ty = tid >> 5;
#pragma unroll
  for (int i = 0; i < 32; i += 8) t[ty + i][tx] = in[(size_t)(r0 + ty + i) * C + c0 + tx];
  __syncthreads();
#pragma unroll
  for (int i = 0; i < 32; i += 8) out[(size_t)(c0 + ty + i) * R + r0 + tx] = f2b(t[tx][ty + i]);
}

// ---------------- QKV GEMM: 128x96 tile, BK=32 double-buffered, T21-swizzled (r22-verified) ----------------
__global__ __launch_bounds__(256) void k_gemmqkv(const u16* __restrict__ A, const u16* __restrict__ Bt,
                                                 u16* __restrict__ Qp, u16* __restrict__ Kp, u16* __restrict__ Vtp){
  __shared__ __align__(16) u16 SM[14336];   // 28 KB; epilogue V-transpose reuse (96x128=12288) fits
  const int tid = threadIdx.x;
  const int w = tid >> 6, l = tid & 63;
  const int m0 = blockIdx.x * 128, n0 = blockIdx.y * 96;
  const int wm = (w >> 1) * 64, wn = (w & 1) * 48;
  const int lg = l >> 4, lr = l & 15;
  f32x4 acc[4][3] = {};

  // staging: thread t -> dest elem 8t (row t>>2, col octet t&3); source logical octet = (t&3)^((t>>2)&3)
  const int tr = tid >> 2;
  const int soct = ((tid & 3) ^ (tr & 3)) * 8;
  const u16* a0 = A  + (size_t)(m0 + tr) * 768 + soct;        // A rows 0-63   (+= 32 per tile)
  const u16* a1 = A  + (size_t)(m0 + 64 + tr) * 768 + soct;   // A rows 64-127
  const u16* b0 = Bt + (size_t)(n0 + tr) * 768 + soct;        // B rows 0-63
  const u16* b1 = Bt + (size_t)(n0 + 64 + tr) * 768 + soct;   // B rows 64-95 (tid<128 only)
  u16* const A0d = SM + 0     + tid*8;  u16* const A0e = SM + 2048  + tid*8;
  u16* const A1d = SM + 4096  + tid*8;  u16* const A1e = SM + 6144  + tid*8;
  u16* const B0d = SM + 8192  + tid*8;  u16* const B0e = SM + 10240 + tid*8;
  u16* const B1d = SM + 11264 + tid*8;  u16* const B1e = SM + 13312 + tid*8;

#define QSTAGE0 do { GLD16(a0, A0d); GLD16(a1, A0e); GLD16(b0, B0d); if (tid < 128) GLD16(b1, B0e); \
                     a0 += 32; a1 += 32; b0 += 32; b1 += 32; } while(0)
#define QSTAGE1 do { GLD16(a0, A1d); GLD16(a1, A1e); GLD16(b0, B1d); if (tid < 128) GLD16(b1, B1e); \
                     a0 += 32; a1 += 32; b0 += 32; b1 += 32; } while(0)

  const int foct = (lg ^ (lr & 3)) * 8;   // fragment read: phys octet of logical octet lg (row&3 == lr&3)

#define QCOMP(ABASE, BBASE) do {                                                            \
    bf16x8 af[4], bfr[3];                                                                   \
    _Pragma("unroll")                                                                       \
    for (int mf = 0; mf < 4; ++mf)                                                          \
      af[mf] = *(const bf16x8*)&SM[(ABASE) + (wm + mf*16 + lr) * 32 + foct];                \
    _Pragma("unroll")                                                                       \
    for (int nf = 0; nf < 3; ++nf)                                                          \
      bfr[nf] = *(const bf16x8*)&SM[(BBASE) + (wn + nf*16 + lr) * 32 + foct];               \
    _Pragma("unroll")                                                                       \
    for (int mf = 0; mf < 4; ++mf)                                                          \
      _Pragma("unroll")                                                                     \
      for (int nf = 0; nf < 3; ++nf)                                                        \
        acc[mf][nf] = __builtin_amdgcn_mfma_f32_16x16x32_bf16(af[mf], bfr[nf], acc[mf][nf], 0, 0, 0); \
  } while(0)

  // prologue: tile 0 -> buf0
  QSTAGE0;
  __syncthreads();
  for (int i = 0; i < 12; ++i){
    QSTAGE1;                 // tile 2i+1 -> buf1 (latency hides under compute)
    QCOMP(0, 8192);          // compute tile 2i from buf0
    __syncthreads();
    if (i < 11) QSTAGE0;     // tile 2i+2 -> buf0
    QCOMP(4096, 11264);      // compute tile 2i+1 from buf1
    __syncthreads();
  }
#undef QSTAGE0
#undef QSTAGE1
#undef QCOMP

  const int which = n0 / 768;
  const int nl0 = n0 - which * 768;
  if (which < 2){
    u16* dst = (which == 0) ? Qp : Kp;
    const float sc = (which == 0) ? 0.125f * LOG2E : 1.0f;
#pragma unroll
    for (int mf = 0; mf < 4; ++mf)
#pragma unroll
      for (int nf = 0; nf < 3; ++nf)
#pragma unroll
        for (int r = 0; r < 4; ++r){
          int m = m0 + wm + mf*16 + lg*4 + r;
          int n = nl0 + wn + nf*16 + lr;
          int b = m >> 11, row = m & 2047, hh = n >> 6, d = n & 63;
          dst[(size_t)((b*12 + hh)*2048 + row) * 64 + d] = f2b(acc[mf][nf][r] * sc);
        }
  } else {
#pragma unroll
    for (int mf = 0; mf < 4; ++mf)
#pragma unroll
      for (int nf = 0; nf < 3; ++nf)
#pragma unroll
        for (int r = 0; r < 4; ++r){
          int mrow = wm + mf*16 + lg*4 + r;
          int c    = wn + nf*16 + lr;
          SM[c * 128 + mrow] = f2b(acc[mf][nf][r]);
        }
    __syncthreads();
#pragma unroll
    for (int rr = 0; rr < 6; ++rr){
      int c  = rr*16 + (tid >> 4);
      int mo = (tid & 15) * 8;
      bf16x8 v = *(const bf16x8*)&SM[c * 128 + mo];
      int n = nl0 + c, hh = n >> 6, d = n & 63;
      int m = m0 + mo, b = m >> 11, key = m & 2047;
      *(bf16x8*)&Vtp[(size_t)((b*12 + hh)*64 + d) * 2048 + key] = v;
    }
  }
}

// ---------------- proj GEMM: 64x64 tile, BK=32 double-buffered, T21-swizzled ----------------
// r23: same two fixes as r22's qkv (old version had 128B-row-stride 16-way bank conflicts AND a
// full vmcnt(0) drain between stage and compute every K-step). BK=32, stage t+1 before compute t,
// XOR-octet swizzle both sides. 1 GLD16/thread per operand per step (dest elem = 8*tid, lane-linear).
// LDS: A0@0 A1@2048 B0@4096 B1@6144 (u16) = 16 KB.
__global__ __launch_bounds__(256) void k_gemm64(const u16* __restrict__ A, const u16* __restrict__ Bt,
                                                float* __restrict__ Co){
  __shared__ __align__(16) u16 SM[8192];
  const int tid = threadIdx.x;
  const int w = tid >> 6, l = tid & 63;
  const int m0 = blockIdx.x * 64, n0 = blockIdx.y * 64;
  const int wm = (w >> 1) * 32, wn = (w & 1) * 32;
  const int lg = l >> 4, lr = l & 15;
  f32x4 acc[2][2] = {};

  // staging: thread t -> dest elem 8t (row t>>2 of 64, col octet t&3); source octet pre-swizzled
  const int tr = tid >> 2;
  const int soct = ((tid & 3) ^ (tr & 3)) * 8;
  const u16* a0 = A  + (size_t)(m0 + tr) * 768 + soct;   // += 32 per tile
  const u16* b0 = Bt + (size_t)(n0 + tr) * 768 + soct;
  u16* const A0d = SM + 0    + tid*8;
  u16* const A1d = SM + 2048 + tid*8;
  u16* const B0d = SM + 4096 + tid*8;
  u16* const B1d = SM + 6144 + tid*8;

#define PSTAGE0 do { GLD16(a0, A0d); GLD16(b0, B0d); a0 += 32; b0 += 32; } while(0)
#define PSTAGE1 do { GLD16(a0, A1d); GLD16(b0, B1d); a0 += 32; b0 += 32; } while(0)

  const int foct = (lg ^ (lr & 3)) * 8;

#define PCOMP(ABASE, BBASE) do {                                                            \
    bf16x8 af[2], bfr[2];                                                                   \
    _Pragma("unroll")                                                                       \
    for (int mf = 0; mf < 2; ++mf)                                                          \
      af[mf] = *(const bf16x8*)&SM[(ABASE) + (wm + mf*16 + lr) * 32 + foct];                \
    _Pragma("unroll")                                                                       \
    for (int nf = 0; nf < 2; ++nf)                                                          \
      bfr[nf] = *(const bf16x8*)&SM[(BBASE) + (wn + nf*16 + lr) * 32 + foct];               \
    _Pragma("unroll")                                                                       \
    for (int mf = 0; mf < 2; ++mf)                                                          \
      _Pragma("unroll")                                                                     \
      for (int nf = 0; nf < 2; ++nf)                                                        \
        acc[mf][nf] = __builtin_amdgcn_mfma_f32_16x16x32_bf16(af[mf], bfr[nf], acc[mf][nf], 0, 0, 0); \
  } while(0)

  PSTAGE0;                   // tile 0 -> buf0
  __syncthreads();
  for (int i = 0; i < 12; ++i){
    PSTAGE1;                 // tile 2i+1 -> buf1
    PCOMP(0, 4096);          // compute tile 2i
    __syncthreads();
    if (i < 11) PSTAGE0;     // tile 2i+2 -> buf0
    PCOMP(2048, 6144);       // compute tile 2i+1
    __syncthreads();
  }
#undef PSTAGE0
#undef PSTAGE1
#undef PCOMP

#pragma unroll
  for (int mf = 0; mf < 2; ++mf)
#pragma unroll
    for (int nf = 0; nf < 2; ++nf)
#pragma unroll
      for (int r = 0; r < 4; ++r)
        Co[(size_t)(m0 + wm + mf*16 + lg*4 + r) * 768 + n0 + wn + nf*16 + lr] = acc[mf][nf][r];
}

// ---------------- flash attention: 8-wave, K+V GLD16-staged, 3-buffer counted-vmcnt(2) ----------------
// (r21-verified, 51.3 µs — FROZEN)
__global__ __launch_bounds__(512, 3) void k_attn(const u16* __restrict__ Qp, const u16* __restrict__ Kp,
                                                 const u16* __restrict__ Vtp, u16* __restrict__ AO){
  __shared__ __align__(16) u16 SM[24576];        // 48 KB: K 3x4096 | V 3x4096; epilogue f32 scratch reuses
  const int tid = threadIdx.x, w = tid >> 6, l = tid & 63;
  const int QH = w >> 1, KH = w & 1;
  const int lg = l >> 4, lr = l & 15;
  const int qt_b = blockIdx.x, bh = blockIdx.y;
  const int b = bh / 12, hh = bh - b * 12;
  const size_t base = (size_t)bh * (2048 * 64);
  const u16* Qg = Qp + base; const u16* Kg = Kp + base; const u16* Vg = Vtp + base;
  const int q0w = qt_b * 64 + QH * 16;
  const int rsw = (lr & 7) * 8;                  // read-side XOR

  // Q B-fragments: qf[ks]: q = q0w + lr, d = ks*32 + lg*8 + j
  bf16x8 qf[2];
#pragma unroll
  for (int ks = 0; ks < 2; ++ks)
    qf[ks] = *(const bf16x8*)&Qg[(size_t)(q0w + lr) * 64 + ks*32 + lg*8];

  f32x4 oacc[4] = {};                            // [nf]: O[d=nf*16+lg*4+r][q=lr] (key-half partial)
  float lp = 0.f;

  // staging: 512 threads x 1 GLD16 each cover the 64x64 u16 K tile and V tile.
  // dest row p_ = tid>>3 (0..63), col octet tid&7; T21 source col16 = (tid&7)^(p_&7).
  // K source rows permuted: srckey(p_) = 32*(p_>>5) + 8*((p_>>2)&3) + 4*((p_>>4)&1) + (p_&3).
  const int p_  = tid >> 3;
  const int sk  = 32*(p_ >> 5) + 8*((p_ >> 2) & 3) + 4*((p_ >> 4) & 1) + (p_ & 3);
  const int cs8 = (((tid & 7) ^ (p_ & 7)) << 3);
  const u16* kp = Kg + (size_t)sk * 64 + cs8;    // induction: += 4096 per tile
  const u16* vp = Vg + ((size_t)p_ << 11) + cs8; // induction: += 64 per tile
  const int drow = p_ * 64;                      // LDS dest offset (u16)
  u16* const K0 = SM + 0     + drow;  u16* const V0 = SM + 12288 + drow;
  u16* const K1 = SM + 4096  + drow;  u16* const V1 = SM + 16384 + drow;
  u16* const K2 = SM + 8192  + drow;  u16* const V2 = SM + 20480 + drow;

  auto compute = [&](const u16* Kc, const u16* Vc){
    f32x4 s[2] = {};                             // s[kf]: C col=lr=q, row=kf*16+4lg+r -> key 8lg+4kf+r
    bf16x8 kfr[2][2];
#pragma unroll
    for (int kf = 0; kf < 2; ++kf)
#pragma unroll
      for (int ks = 0; ks < 2; ++ks)
        kfr[kf][ks] = *(const bf16x8*)&Kc[(KH*32 + kf*16 + lr) * 64 + ((ks*32 + lg*8) ^ rsw)];
    __builtin_amdgcn_s_setprio(1);
#pragma unroll
    for (int ks = 0; ks < 2; ++ks)
#pragma unroll
      for (int kf = 0; kf < 2; ++kf)
        s[kf] = __builtin_amdgcn_mfma_f32_16x16x32_bf16(kfr[kf][ks], qf[ks], s[kf], 0, 0, 0);
    __builtin_amdgcn_s_setprio(0);

    // P = exp2(S'); B-frag slot j: j=0..3 from s[0], j=4..7 from s[1] (key = KH*32 + 8lg + j)
    float p00 = __builtin_exp2f(s[0][0]);
    float p01 = __builtin_exp2f(s[0][1]);
    float p02 = __builtin_exp2f(s[0][2]);
    float p03 = __builtin_exp2f(s[0][3]);
    float p10 = __builtin_exp2f(s[1][0]);
    float p11 = __builtin_exp2f(s[1][1]);
    float p12 = __builtin_exp2f(s[1][2]);
    float p13 = __builtin_exp2f(s[1][3]);
    lp += ((p00 + p01) + (p02 + p03)) + ((p10 + p11) + (p12 + p13));
    union { uint32_t u[4]; bf16x8 v; } fr;
    fr.u[0] = pkrhu(p00, p01);
    fr.u[1] = pkrhu(p02, p03);
    fr.u[2] = pkrhu(p10, p11);
    fr.u[3] = pkrhu(p12, p13);

    bf16x8 vfr[4];
#pragma unroll
    for (int nf = 0; nf < 4; ++nf)
      vfr[nf] = *(const bf16x8*)&Vc[(nf*16 + lr) * 64 + ((KH*32 + lg*8) ^ rsw)];
    __builtin_amdgcn_s_setprio(1);
#pragma unroll
    for (int nf = 0; nf < 4; ++nf)
      oacc[nf] = __builtin_amdgcn_mfma_f32_16x16x32_bf16(vfr[nf], fr.v, oacc[nf], 0, 0, 0);
    __builtin_amdgcn_s_setprio(0);
  };

#define STAGE2(KD, VD) do { GLD16(kp, KD); GLD16(vp, VD); kp += 4096; vp += 64; } while(0)
#define BAR_CNT2  do { asm volatile("s_waitcnt vmcnt(2)" ::: "memory"); \
                       __builtin_amdgcn_s_barrier(); __builtin_amdgcn_sched_barrier(0); } while(0)
#define BAR_CNT0  do { asm volatile("s_waitcnt vmcnt(0)" ::: "memory"); \
                       __builtin_amdgcn_s_barrier(); __builtin_amdgcn_sched_barrier(0); } while(0)

  // prologue: stage t0->buf0, t1->buf1; ensure t0 landed (t1's 2 loads may remain in flight)
  STAGE2(K0, V0);
  STAGE2(K1, V1);
  BAR_CNT2;

  for (int g = 0; g < 10; ++g){
    STAGE2(K2, V2);  compute(SM + 0,    SM + 12288);  BAR_CNT2;   // t=3g
    STAGE2(K0, V0);  compute(SM + 4096, SM + 16384);  BAR_CNT2;   // t=3g+1
    STAGE2(K1, V1);  compute(SM + 8192, SM + 20480);  BAR_CNT2;   // t=3g+2
  }
  compute(SM + 0,    SM + 12288);   // t=30
  BAR_CNT0;                         // ensure t=31 landed
  compute(SM + 4096, SM + 16384);   // t=31

#undef STAGE2
#undef BAR_CNT2
#undef BAR_CNT0

  // per-q row sum over this wave's key half (q = lr; reduce over lg lanes)
  float lt = lp;
  lt += __shfl_xor(lt, 16);
  lt += __shfl_xor(lt, 32);

  __syncthreads();   // full sync before reusing SM as f32 scratch
  // split-key merge (pure sums under no-max): KH=1 publishes, KH=0 merges + stores.
  float* Osc = (float*)SM;                        // [64 q][65] f32 (stride 65, conflict-free)
  float* Lsc = Osc + 64 * 65;                     // [64 q] f32  (total 16896 B <= 49152 B)
  if (KH == 1){
#pragma unroll
    for (int nf = 0; nf < 4; ++nf)
#pragma unroll
      for (int r = 0; r < 4; ++r)
        Osc[(QH*16 + lr) * 65 + nf*16 + lg*4 + r] = oacc[nf][r];
    if (lg == 0) Lsc[QH*16 + lr] = lt;
  }
  __syncthreads();
  if (KH == 0){
    float inv = 1.0f / (lt + Lsc[QH*16 + lr]);
#pragma unroll
    for (int nf = 0; nf < 4; ++nf)
#pragma unroll
      for (int r = 0; r < 4; ++r){
        float o = oacc[nf][r] + Osc[(QH*16 + lr) * 65 + nf*16 + lg*4 + r];
        AO[(size_t)((b << 11) + q0w + lr) * 768 + hh*64 + nf*16 + lg*4 + r] = f2b(o * inv);
      }
  }
}

extern "C" void kernel_launch(void* const* d_in, const int* in_sizes, int n_in,
                              void* d_out, int out_size, void* d_ws, size_t ws_size,
                              hipStream_t stream){
  const float* x      = (const float*)d_in[0];
  const float* w_qkv  = (const float*)d_in[1];
  const float* w_proj = (const float*)d_in[2];
  float* out = (float*)d_out;
  char* ws = (char*)d_ws;
  u16* Xb     = (u16*)(ws + 0);
  u16* WqkvT  = (u16*)(ws + 6291456);
  u16* WprojT = (u16*)(ws + 9830400);
  u16* Qp     = (u16*)(ws + 11010048);
  u16* Kp     = (u16*)(ws + 17301504);
  u16* Vtp    = (u16*)(ws + 23592960);
  u16* AO     = (u16*)(ws + 29884416);

  k_prep<<<3840, 256, 0, stream>>>(x, Xb, w_qkv, WqkvT, w_proj, WprojT);
  k_gemmqkv<<<dim3(32, 24), 256, 0, stream>>>(Xb, WqkvT, Qp, Kp, Vtp);
  k_attn<<<dim3(32, 24), 512, 0, stream>>>(Qp, Kp, Vtp, AO);
  k_gemm64<<<dim3(64, 12), 256, 0, stream>>>(AO, WprojT, out);
}